// Round 14
// baseline (160.772 us; speedup 1.0000x reference)
//
#include <hip/hip_runtime.h>
#include <hip/hip_bf16.h>

typedef short s16x8 __attribute__((ext_vector_type(8)));
typedef float f32x4 __attribute__((ext_vector_type(4)));
typedef float f32x16 __attribute__((ext_vector_type(16)));
typedef unsigned short u16x4 __attribute__((ext_vector_type(4)));
typedef unsigned int u32x4 __attribute__((ext_vector_type(4)));

#define D_MODEL 1024
#define N_HEAD  16
#define D_HEAD  64
#define SEQ     2048
#define NBATCH  2

#if __has_builtin(__builtin_amdgcn_exp2f)
#define EXP2(x) __builtin_amdgcn_exp2f(x)
#else
#define EXP2(x) exp2f(x)
#endif

#define GLOAD_LDS16(g, l) \
    __builtin_amdgcn_global_load_lds((const __attribute__((address_space(1))) void*)(g), \
                                     (__attribute__((address_space(3))) void*)(l), 16, 0, 0)

__device__ __forceinline__ unsigned short f2bf(float f) {
    union { float f; unsigned int u; } v; v.f = f;
    unsigned int r = v.u + 0x7FFFu + ((v.u >> 16) & 1u);
    return (unsigned short)(r >> 16);
}

__device__ __forceinline__ float bf2f(unsigned short u) {
    union { unsigned int u; float f; } v; v.u = ((unsigned int)u) << 16;
    return v.f;
}

__device__ __forceinline__ unsigned cvtpk_bf16(float lo, float hi) {
    unsigned r;
    asm("v_cvt_pk_bf16_f32 %0, %1, %2" : "=v"(r) : "v"(lo), "v"(hi));
    return r;
}

// item tables: 30 types, descending size (full-12 chunks first). s = strip, c = chunk idx.
__device__ const unsigned char T_S[30] = {5,6,7,8,9,10,11,11,12,12,13,13,14,14,15,15,
                                          4,10, 3,9,15, 2,8,14, 1,7,13, 0,6,12};
__device__ const unsigned char T_C[30] = {0,0,0,0,0,0,0,1,0,1,0,1,0,1,0,1,
                                          0,1, 0,1,2, 0,1,2, 0,1,2, 0,1,2};

// ---------------- fused conversion: x (4096 blocks) + 4 weights (1024 blocks) -------------

__global__ __launch_bounds__(256) void cvt_all_kernel(
    const float* __restrict__ x, unsigned short* __restrict__ xb,
    const float* __restrict__ w0, const float* __restrict__ w1,
    const float* __restrict__ w2, const float* __restrict__ w3,
    unsigned short* __restrict__ o0, unsigned short* __restrict__ o1,
    unsigned short* __restrict__ o2, unsigned short* __restrict__ o3)
{
    __shared__ unsigned short T[64][72];
    const int t = threadIdx.x;
    const int bid = blockIdx.x;
    if (bid < 4096) {
        int i = (bid * 256 + t) * 4;
        float4 v = *reinterpret_cast<const float4*>(x + i);
        u16x4 o;
        o.x = f2bf(v.x); o.y = f2bf(v.y); o.z = f2bf(v.z); o.w = f2bf(v.w);
        *reinterpret_cast<u16x4*>(xb + i) = o;
        return;
    }
    const int u = bid - 4096;
    const int z = u >> 8, tile = u & 255;
    const float* w = (z == 0) ? w0 : (z == 1) ? w1 : (z == 2) ? w2 : w3;
    unsigned short* wt = (z == 0) ? o0 : (z == 1) ? o1 : (z == 2) ? o2 : o3;
    const int k0 = (tile & 15) * 64, n0 = (tile >> 4) * 64;
#pragma unroll
    for (int i = 0; i < 4; ++i) {
        int k = (t >> 4) + i * 16;
        int n = (t & 15) * 4;
        float4 v = *reinterpret_cast<const float4*>(&w[(k0 + k) * 1024 + n0 + n]);
        T[n + 0][k] = f2bf(v.x); T[n + 1][k] = f2bf(v.y);
        T[n + 2][k] = f2bf(v.z); T[n + 3][k] = f2bf(v.w);
    }
    __syncthreads();
#pragma unroll
    for (int i = 0; i < 2; ++i) {
        int n = (t >> 3) + i * 32;
        int kc = (t & 7) * 8;
        *reinterpret_cast<s16x8*>(&wt[(n0 + n) * 1024 + k0 + kc]) =
            *reinterpret_cast<const s16x8*>(&T[n][kc]);
    }
}

// ---------------- gemm_qkv: 128x128 tiles, BK=64, swizzled LDS + XCD block swizzle --------

__global__ __launch_bounds__(256, 3) void gemm_qkv_kernel(
    const unsigned short* __restrict__ xb,
    const unsigned short* __restrict__ wqt, const unsigned short* __restrict__ wkt,
    const unsigned short* __restrict__ wvt,
    unsigned short* __restrict__ Qb, unsigned short* __restrict__ Kb,
    unsigned short* __restrict__ Vtb)
{
    __shared__ unsigned short As[128 * 64];
    __shared__ unsigned short Bs[128 * 64];
    const int t = threadIdx.x, lane = t & 63, wid = t >> 6;
    const int wr = wid >> 1, wc = wid & 1;
    const int l15 = lane & 15, l4 = lane >> 4;

    const int orig = blockIdx.x;
    const int wg = (orig & 7) * 96 + (orig >> 3);
    const int z = wg >> 8;
    const int rem = wg & 255;
    const int m0 = (rem >> 3) * 128, n0 = (rem & 7) * 128;
    const unsigned short* Bt = (z == 0) ? wqt : (z == 1) ? wkt : wvt;

    const int srow = t >> 3;
    const int srcoff = (((t & 7) ^ (srow & 7)) << 3);
    const unsigned short* Ab = xb + (size_t)(m0 + srow) * D_MODEL + srcoff;
    const unsigned short* Bb = Bt + (size_t)(n0 + srow) * D_MODEL + srcoff;
    const int ldsoff = t * 8;
    const int rsw = l15 & 7;

    f32x4 acc[4][4];
#pragma unroll
    for (int m = 0; m < 4; ++m)
#pragma unroll
        for (int n = 0; n < 4; ++n) acc[m][n] = (f32x4){0.f, 0.f, 0.f, 0.f};

    for (int k0 = 0; k0 < D_MODEL; k0 += 64) {
        __syncthreads();
#pragma unroll
        for (int i = 0; i < 4; ++i) {
            GLOAD_LDS16(Ab + (size_t)(i * 32) * D_MODEL + k0, &As[i * 2048 + ldsoff]);
            GLOAD_LDS16(Bb + (size_t)(i * 32) * D_MODEL + k0, &Bs[i * 2048 + ldsoff]);
        }
        __syncthreads();

#pragma unroll
        for (int ks = 0; ks < 2; ++ks) {
            const int csl = ks * 4 + l4;
            s16x8 af[4], bfr[4];
#pragma unroll
            for (int m = 0; m < 4; ++m)
                af[m] = *reinterpret_cast<const s16x8*>(
                    &As[(wr * 64 + m * 16 + l15) * 64 + ((csl ^ rsw) << 3)]);
#pragma unroll
            for (int n = 0; n < 4; ++n)
                bfr[n] = *reinterpret_cast<const s16x8*>(
                    &Bs[(wc * 64 + n * 16 + l15) * 64 + ((csl ^ rsw) << 3)]);
            __builtin_amdgcn_s_setprio(1);
#pragma unroll
            for (int m = 0; m < 4; ++m)
#pragma unroll
                for (int n = 0; n < 4; ++n)
                    acc[m][n] = __builtin_amdgcn_mfma_f32_16x16x32_bf16(af[m], bfr[n], acc[m][n], 0, 0, 0);
            __builtin_amdgcn_s_setprio(0);
        }
    }

    const int rb = m0 + wr * 64, cb = n0 + wc * 64;
    if (z == 2) {
#pragma unroll
        for (int m = 0; m < 4; ++m) {
            int row = rb + m * 16 + l4 * 4;
            int b = row >> 11, s = row & 2047;
#pragma unroll
            for (int n = 0; n < 4; ++n) {
                int col = cb + n * 16 + l15;
                int h = col >> 6, dk = col & 63;
                u16x4 o;
                o.x = f2bf(acc[m][n][0]); o.y = f2bf(acc[m][n][1]);
                o.z = f2bf(acc[m][n][2]); o.w = f2bf(acc[m][n][3]);
                *reinterpret_cast<u16x4*>(&Vtb[(((b * N_HEAD + h) * D_HEAD + dk) << 11) + s]) = o;
            }
        }
    } else {
        unsigned short* C = (z == 0) ? Qb : Kb;
        const float alpha = (z == 0) ? 0.18033688011112042f : 1.0f;  // (1/8)*log2(e)
#pragma unroll
        for (int m = 0; m < 4; ++m)
#pragma unroll
            for (int n = 0; n < 4; ++n)
#pragma unroll
                for (int r = 0; r < 4; ++r)
                    C[(rb + m * 16 + l4 * 4 + r) * D_MODEL + cb + n * 16 + l15] =
                        f2bf(acc[m][n][r] * alpha);
    }
}

// ---------------- gemm_out: 128x64 tiles, BK=64; combine FUSED into A-staging -------------
// Each block's A-tile is one 128-row strip; each K-step is one head h = k0>>6.
// Strips s<6: global_load_lds direct (fast path). s>=6: reg-stage = sum 2-3 Opart slots,
// normalize by sum(larr), cvt_pk -> swizzled ds_write. combine_kernel eliminated.

__global__ __launch_bounds__(256, 3) void gemm_out_kernel(
    const unsigned short* __restrict__ attnb,
    const unsigned short* __restrict__ Opart, const float* __restrict__ larr,
    const unsigned short* __restrict__ wot, float* __restrict__ out)
{
    __shared__ unsigned short As[128 * 64];
    __shared__ unsigned short Bs[64 * 64];
    const int t = threadIdx.x, lane = t & 63, wid = t >> 6;
    const int wr = wid >> 1, wc = wid & 1;
    const int l15 = lane & 15, l4 = lane >> 4;

    const int orig = blockIdx.x;
    const int wg = (orig & 7) * 64 + (orig >> 3);
    const int m0 = (wg >> 4) * 128, n0 = (wg & 15) * 64;

    const int bq = m0 >> 11, sst = (m0 & 2047) >> 7;
    const bool split = (sst >= 6);
    const int soff = (sst < 12) ? (sst - 6) * 2 : 12 + (sst - 12) * 3;
    const int nsl = (sst < 12) ? 2 : 3;

    const int srow = t >> 3;
    const int cg = t & 7;
    const int srcoff = ((cg ^ (srow & 7)) << 3);
    const unsigned short* Ab = attnb + (size_t)(m0 + srow) * D_MODEL + srcoff;
    const unsigned short* Bb = wot + (size_t)(n0 + srow) * D_MODEL + srcoff;
    const int ldsoff = t * 8;
    const int rsw = l15 & 7;

    f32x4 acc[4][2];
#pragma unroll
    for (int m = 0; m < 4; ++m)
#pragma unroll
        for (int n = 0; n < 2; ++n) acc[m][n] = (f32x4){0.f, 0.f, 0.f, 0.f};

    for (int k0 = 0; k0 < D_MODEL; k0 += 64) {
        __syncthreads();
        if (!split) {
#pragma unroll
            for (int i = 0; i < 4; ++i)
                GLOAD_LDS16(Ab + (size_t)(i * 32) * D_MODEL + k0, &As[i * 2048 + ldsoff]);
        } else {
            const int h = k0 >> 6;
            const int slot0 = (bq * 16 + h) * 24 + soff;
#pragma unroll
            for (int i = 0; i < 4; ++i) {
                const int row = i * 32 + srow;
                float lsum = larr[slot0 * 128 + row] + larr[(slot0 + 1) * 128 + row];
                if (nsl == 3) lsum += larr[(slot0 + 2) * 128 + row];
                const float inv = 1.0f / lsum;
                const unsigned short* pa = Opart + (size_t)slot0 * 8192 + row * 64 + cg * 8;
                s16x8 va = *reinterpret_cast<const s16x8*>(pa);
                s16x8 vb = *reinterpret_cast<const s16x8*>(pa + 8192);
                float sm[8];
#pragma unroll
                for (int j = 0; j < 8; ++j)
                    sm[j] = bf2f((unsigned short)va[j]) + bf2f((unsigned short)vb[j]);
                if (nsl == 3) {
                    s16x8 vc = *reinterpret_cast<const s16x8*>(pa + 16384);
#pragma unroll
                    for (int j = 0; j < 8; ++j) sm[j] += bf2f((unsigned short)vc[j]);
                }
                u32x4 pw;
                pw.x = cvtpk_bf16(sm[0] * inv, sm[1] * inv);
                pw.y = cvtpk_bf16(sm[2] * inv, sm[3] * inv);
                pw.z = cvtpk_bf16(sm[4] * inv, sm[5] * inv);
                pw.w = cvtpk_bf16(sm[6] * inv, sm[7] * inv);
                *reinterpret_cast<u32x4*>(&As[row * 64 + srcoff]) = pw;
            }
        }
#pragma unroll
        for (int i = 0; i < 2; ++i)
            GLOAD_LDS16(Bb + (size_t)(i * 32) * D_MODEL + k0, &Bs[i * 2048 + ldsoff]);
        __syncthreads();

#pragma unroll
        for (int ks = 0; ks < 2; ++ks) {
            const int csl = ks * 4 + l4;
            s16x8 af[4], bfr[2];
#pragma unroll
            for (int m = 0; m < 4; ++m)
                af[m] = *reinterpret_cast<const s16x8*>(
                    &As[(wr * 64 + m * 16 + l15) * 64 + ((csl ^ rsw) << 3)]);
#pragma unroll
            for (int n = 0; n < 2; ++n)
                bfr[n] = *reinterpret_cast<const s16x8*>(
                    &Bs[(wc * 32 + n * 16 + l15) * 64 + ((csl ^ rsw) << 3)]);
            __builtin_amdgcn_s_setprio(1);
#pragma unroll
            for (int m = 0; m < 4; ++m)
#pragma unroll
                for (int n = 0; n < 2; ++n)
                    acc[m][n] = __builtin_amdgcn_mfma_f32_16x16x32_bf16(af[m], bfr[n], acc[m][n], 0, 0, 0);
            __builtin_amdgcn_s_setprio(0);
        }
    }

    const int rb = m0 + wr * 64, cb = n0 + wc * 32;
#pragma unroll
    for (int m = 0; m < 4; ++m)
#pragma unroll
        for (int n = 0; n < 2; ++n)
#pragma unroll
            for (int r = 0; r < 4; ++r)
                out[(rb + m * 16 + l4 * 4 + r) * D_MODEL + cb + n * 16 + l15] = acc[m][n][r];
}

// ---------------- flash attention v10: v8 + MFMA row-sum (l via ones-MFMA) ----------------
// l = sum_kv P computed as lacc = mfma(ones, pf, lacc) on the idle matrix pipe; removes the
// per-tile 31-op VALU sum tree AND the cross-half shuffle from the serial critical path.

__global__ __launch_bounds__(256, 4) void attn_kernel(
    const unsigned short* __restrict__ Qb, const unsigned short* __restrict__ Kb,
    const unsigned short* __restrict__ Vtb, unsigned short* __restrict__ Ob,
    unsigned short* __restrict__ Opart, float* __restrict__ larr)
{
    __shared__ unsigned short SMEM[8192];       // K dbuf [2][4096]
    __shared__ unsigned short SMEMV[8192];      // V dbuf [2][4096]

    const int t = threadIdx.x;
    const int lane = t & 63, wid = t >> 6;      // 4 waves
    const int l31 = lane & 31, l5 = lane >> 5;

    const int bid = blockIdx.x;                 // 0..959
    const int type = bid >> 5, bh = bid & 31;
    const int s = T_S[type], c = T_C[type];
    const int ta = c * 12;
    const int tbf = 2 * (s + 1);
    const int tb = (ta + 12 < tbf) ? ta + 12 : tbf;
    const bool split = (s >= 6);
    const int slot = bh * 24 + ((s < 12) ? (s - 6) * 2 + c : 12 + (s - 12) * 3 + c);

    const int b = bh >> 4, h = bh & 15;
    const int q0 = s << 7;
    const int qw = q0 + wid * 32;
    const int qrow = qw + l31;

    s16x8 qf[4];
#pragma unroll
    for (int ks = 0; ks < 4; ++ks)
        qf[ks] = *reinterpret_cast<const s16x8*>(
            &Qb[(size_t)(b * SEQ + qrow) * D_MODEL + h * D_HEAD + ks * 16 + l5 * 8]);

    const short oneb = (short)0x3F80;           // bf16 1.0
    const s16x8 onesf = {oneb, oneb, oneb, oneb, oneb, oneb, oneb, oneb};

    f32x16 oacc[2], lacc;
#pragma unroll
    for (int d = 0; d < 2; ++d)
#pragma unroll
        for (int r = 0; r < 16; ++r) oacc[d][r] = 0.f;
#pragma unroll
    for (int r = 0; r < 16; ++r) lacc[r] = 0.f;

    const int stK = (wid & 1) * 32;
    const int srow = lane >> 3;
    const int scol = ((lane & 7) ^ srow) * 8;
    const unsigned short* kgb = Kb + (size_t)(b * SEQ + stK + srow) * D_MODEL + h * D_HEAD + scol;
    const unsigned short* vgb = Vtb + ((size_t)(bh * D_HEAD + stK + srow) << 11) + scol;
    const int swz = (l31 & 7);

#define STAGE(bufidx, kvbase) do { \
    if (wid < 2) { \
        const unsigned short* kg = kgb + (size_t)(kvbase) * D_MODEL; \
        _Pragma("unroll") \
        for (int i_ = 0; i_ < 4; ++i_) \
            GLOAD_LDS16(kg + (size_t)(i_ * 8) * D_MODEL, &SMEM[(bufidx) * 4096 + (stK + i_ * 8) * 64]); \
    } else { \
        const unsigned short* vg = vgb + (kvbase); \
        _Pragma("unroll") \
        for (int i_ = 0; i_ < 4; ++i_) \
            GLOAD_LDS16(vg + ((size_t)(i_ * 8) << 11), &SMEMV[(bufidx) * 4096 + (stK + i_ * 8) * 64]); \
    } } while (0)

    STAGE(0, ta * 64);

    for (int ti = ta; ti < tb; ++ti) {
        const int cur = (ti - ta) & 1;
        const int kv0 = ti * 64;
        __builtin_amdgcn_sched_barrier(0);
        asm volatile("s_waitcnt vmcnt(0)" ::: "memory");
        __builtin_amdgcn_s_barrier();
        if (ti + 1 < tb) STAGE(cur ^ 1, (ti + 1) * 64);
        __builtin_amdgcn_sched_barrier(0);

        if (kv0 > qw + 31) continue;

        const unsigned short* KsC = &SMEM[cur * 4096];
        const unsigned short* VsC = &SMEMV[cur * 4096];

        f32x16 sacc[2];
#pragma unroll
        for (int kvsub = 0; kvsub < 2; ++kvsub) {
            const bool active = (kv0 + kvsub * 32 <= qw + 31);
            if (active) {
#pragma unroll
                for (int r = 0; r < 16; ++r) sacc[kvsub][r] = -8.0f;
                __builtin_amdgcn_s_setprio(1);
#pragma unroll
                for (int ks = 0; ks < 4; ++ks) {
                    s16x8 kf = *reinterpret_cast<const s16x8*>(
                        &KsC[(kvsub * 32 + l31) * 64 + (((2 * ks + l5) ^ swz) * 8)]);
                    sacc[kvsub] = __builtin_amdgcn_mfma_f32_32x32x16_bf16(kf, qf[ks], sacc[kvsub], 0, 0, 0);
                }
                __builtin_amdgcn_s_setprio(0);
                if (kv0 + kvsub * 32 + 31 > qw) {
                    int kvbase = kv0 + kvsub * 32 + 4 * l5;
#pragma unroll
                    for (int r = 0; r < 16; ++r) {
                        int kvg = kvbase + (r & 3) + 8 * (r >> 2);
                        sacc[kvsub][r] = (kvg > qrow) ? -1e30f : sacc[kvsub][r];
                    }
                }
#pragma unroll
                for (int r = 0; r < 16; ++r) sacc[kvsub][r] = EXP2(sacc[kvsub][r]);
            } else {
#pragma unroll
                for (int r = 0; r < 16; ++r) sacc[kvsub][r] = 0.f;
            }
        }

        // ---- P -> bf16 (cvt_pk + permlane32_swap) + PV + l-accum on MFMA pipe ----
#pragma unroll
        for (int ks = 0; ks < 4; ++ks) {
            if (kv0 + (ks >> 1) * 32 > qw + 31) continue;
            const int kvsub = ks >> 1, bo = (ks & 1) * 8;
            unsigned a0 = cvtpk_bf16(sacc[kvsub][bo + 0], sacc[kvsub][bo + 1]);
            unsigned a1 = cvtpk_bf16(sacc[kvsub][bo + 2], sacc[kvsub][bo + 3]);
            unsigned a2 = cvtpk_bf16(sacc[kvsub][bo + 4], sacc[kvsub][bo + 5]);
            unsigned a3 = cvtpk_bf16(sacc[kvsub][bo + 6], sacc[kvsub][bo + 7]);
            asm volatile("v_permlane32_swap_b32 %0, %1" : "+v"(a0), "+v"(a2));
            asm volatile("v_permlane32_swap_b32 %0, %1" : "+v"(a1), "+v"(a3));
            u32x4 pw; pw.x = a0; pw.y = a1; pw.z = a2; pw.w = a3;
            s16x8 pf = __builtin_bit_cast(s16x8, pw);
            __builtin_amdgcn_s_setprio(1);
            lacc = __builtin_amdgcn_mfma_f32_32x32x16_bf16(onesf, pf, lacc, 0, 0, 0);
#pragma unroll
            for (int dsub = 0; dsub < 2; ++dsub) {
                s16x8 vf = *reinterpret_cast<const s16x8*>(
                    &VsC[(dsub * 32 + l31) * 64 + (((2 * ks + l5) ^ swz) * 8)]);
                oacc[dsub] = __builtin_amdgcn_mfma_f32_32x32x16_bf16(vf, pf, oacc[dsub], 0, 0, 0);
            }
            __builtin_amdgcn_s_setprio(0);
        }
    }
    __syncthreads();

    const float lrun = lacc[0];                 // all rows identical = sum_kv P[kv][q=lane&31]
    float inv = split ? 1.0f : (1.0f / lrun);
    const int orow = wid * 32 + l31;
#pragma unroll
    for (int dsub = 0; dsub < 2; ++dsub)
#pragma unroll
        for (int a = 0; a < 4; ++a) {
            unsigned w0 = cvtpk_bf16(oacc[dsub][4 * a + 0] * inv, oacc[dsub][4 * a + 1] * inv);
            unsigned w1 = cvtpk_bf16(oacc[dsub][4 * a + 2] * inv, oacc[dsub][4 * a + 3] * inv);
            int slt = (4 * dsub + a) ^ (orow & 7);
            uint2 pr; pr.x = w0; pr.y = w1;
            *reinterpret_cast<uint2*>(&SMEM[orow * 64 + slt * 8 + l5 * 4]) = pr;
        }
    __syncthreads();
    if (split) {
        unsigned short* Op = Opart + (size_t)slot * 8192;
#pragma unroll
        for (int i = 0; i < 4; ++i) {
            int g = i * 256 + t;
            int row = g >> 3, c16 = g & 7;
            int cs = (c16 ^ (row & 7)) * 8;
            *reinterpret_cast<s16x8*>(&Op[row * 64 + c16 * 8]) =
                *reinterpret_cast<const s16x8*>(&SMEM[row * 64 + cs]);
        }
        if (l5 == 0) larr[slot * 128 + orow] = lrun;
    } else {
#pragma unroll
        for (int i = 0; i < 4; ++i) {
            int g = i * 256 + t;
            int row = g >> 3, c16 = g & 7;
            int cs = (c16 ^ (row & 7)) * 8;
            s16x8 v = *reinterpret_cast<const s16x8*>(&SMEM[row * 64 + cs]);
            *reinterpret_cast<s16x8*>(
                &Ob[(size_t)(b * SEQ + q0 + row) * D_MODEL + h * D_HEAD + c16 * 8]) = v;
        }
    }
#undef STAGE
}

// ---------------- launch ----------------

extern "C" void kernel_launch(void* const* d_in, const int* in_sizes, int n_in,
                              void* d_out, int out_size, void* d_ws, size_t ws_size,
                              hipStream_t stream) {
    (void)in_sizes; (void)n_in; (void)out_size; (void)ws_size;
    const float* x  = (const float*)d_in[0];
    const float* wq = (const float*)d_in[1];
    const float* wk = (const float*)d_in[2];
    const float* wv = (const float*)d_in[3];
    const float* wo = (const float*)d_in[4];
    float* out = (float*)d_out;

    char* ws = (char*)d_ws;
    unsigned short* xb  = (unsigned short*)(ws);
    unsigned short* wqt = (unsigned short*)(ws + (8u  << 20));
    unsigned short* wkt = (unsigned short*)(ws + (10u << 20));
    unsigned short* wvt = (unsigned short*)(ws + (12u << 20));
    unsigned short* wot = (unsigned short*)(ws + (14u << 20));
    unsigned short* Qb  = (unsigned short*)(ws + (16u << 20));
    unsigned short* Kb  = (unsigned short*)(ws + (24u << 20));
    unsigned short* Vtb = (unsigned short*)(ws + (32u << 20));
    unsigned short* Ob  = (unsigned short*)(ws + (40u << 20));
    unsigned short* Opart = xb;                       // 768 slots x 128x64 bf16 = 12 MB
    float*          larr  = (float*)wvt;              // 768 x 128 fp32 (dead after qkv)

    hipLaunchKernelGGL(cvt_all_kernel, dim3(5120), dim3(256), 0, stream,
                       x, xb, wq, wk, wv, wo, wqt, wkt, wvt, wot);

    hipLaunchKernelGGL(gemm_qkv_kernel, dim3(768), dim3(256), 0, stream,
                       xb, wqt, wkt, wvt, Qb, Kb, Vtb);
    hipLaunchKernelGGL(attn_kernel, dim3(960), dim3(256), 0, stream,
                       Qb, Kb, Vtb, Ob, Opart, larr);
    hipLaunchKernelGGL(gemm_out_kernel, dim3(512), dim3(256), 0, stream,
                       Ob, Opart, larr, wot, out);
}

// Round 15
// 104.474 us; speedup vs baseline: 1.5389x; 1.5389x over previous
//
#include <hip/hip_runtime.h>
#include <hip/hip_bf16.h>

typedef short s16x8 __attribute__((ext_vector_type(8)));
typedef float f32x4 __attribute__((ext_vector_type(4)));
typedef float f32x16 __attribute__((ext_vector_type(16)));
typedef unsigned short u16x4 __attribute__((ext_vector_type(4)));
typedef unsigned int u32x4 __attribute__((ext_vector_type(4)));

#define D_MODEL 1024
#define N_HEAD  16
#define D_HEAD  64
#define SEQ     2048
#define NBATCH  2

#if __has_builtin(__builtin_amdgcn_exp2f)
#define EXP2(x) __builtin_amdgcn_exp2f(x)
#else
#define EXP2(x) exp2f(x)
#endif

#define GLOAD_LDS16(g, l) \
    __builtin_amdgcn_global_load_lds((const __attribute__((address_space(1))) void*)(g), \
                                     (__attribute__((address_space(3))) void*)(l), 16, 0, 0)

__device__ __forceinline__ unsigned short f2bf(float f) {
    union { float f; unsigned int u; } v; v.f = f;
    unsigned int r = v.u + 0x7FFFu + ((v.u >> 16) & 1u);
    return (unsigned short)(r >> 16);
}

__device__ __forceinline__ float bf2f(unsigned short u) {
    union { unsigned int u; float f; } v; v.u = ((unsigned int)u) << 16;
    return v.f;
}

__device__ __forceinline__ unsigned cvtpk_bf16(float lo, float hi) {
    unsigned r;
    asm("v_cvt_pk_bf16_f32 %0, %1, %2" : "=v"(r) : "v"(lo), "v"(hi));
    return r;
}

// item tables: 30 types, descending size (full-12 chunks first). s = strip, c = chunk idx.
__device__ const unsigned char T_S[30] = {5,6,7,8,9,10,11,11,12,12,13,13,14,14,15,15,
                                          4,10, 3,9,15, 2,8,14, 1,7,13, 0,6,12};
__device__ const unsigned char T_C[30] = {0,0,0,0,0,0,0,1,0,1,0,1,0,1,0,1,
                                          0,1, 0,1,2, 0,1,2, 0,1,2, 0,1,2};

// ---------------- fused conversion: x (4096 blocks) + 4 weights (1024 blocks) -------------

__global__ __launch_bounds__(256) void cvt_all_kernel(
    const float* __restrict__ x, unsigned short* __restrict__ xb,
    const float* __restrict__ w0, const float* __restrict__ w1,
    const float* __restrict__ w2, const float* __restrict__ w3,
    unsigned short* __restrict__ o0, unsigned short* __restrict__ o1,
    unsigned short* __restrict__ o2, unsigned short* __restrict__ o3)
{
    __shared__ unsigned short T[64][72];
    const int t = threadIdx.x;
    const int bid = blockIdx.x;
    if (bid < 4096) {
        int i = (bid * 256 + t) * 4;
        float4 v = *reinterpret_cast<const float4*>(x + i);
        u16x4 o;
        o.x = f2bf(v.x); o.y = f2bf(v.y); o.z = f2bf(v.z); o.w = f2bf(v.w);
        *reinterpret_cast<u16x4*>(xb + i) = o;
        return;
    }
    const int u = bid - 4096;
    const int z = u >> 8, tile = u & 255;
    const float* w = (z == 0) ? w0 : (z == 1) ? w1 : (z == 2) ? w2 : w3;
    unsigned short* wt = (z == 0) ? o0 : (z == 1) ? o1 : (z == 2) ? o2 : o3;
    const int k0 = (tile & 15) * 64, n0 = (tile >> 4) * 64;
#pragma unroll
    for (int i = 0; i < 4; ++i) {
        int k = (t >> 4) + i * 16;
        int n = (t & 15) * 4;
        float4 v = *reinterpret_cast<const float4*>(&w[(k0 + k) * 1024 + n0 + n]);
        T[n + 0][k] = f2bf(v.x); T[n + 1][k] = f2bf(v.y);
        T[n + 2][k] = f2bf(v.z); T[n + 3][k] = f2bf(v.w);
    }
    __syncthreads();
#pragma unroll
    for (int i = 0; i < 2; ++i) {
        int n = (t >> 3) + i * 32;
        int kc = (t & 7) * 8;
        *reinterpret_cast<s16x8*>(&wt[(n0 + n) * 1024 + k0 + kc]) =
            *reinterpret_cast<const s16x8*>(&T[n][kc]);
    }
}

// ---------------- gemm_qkv: 128x128 tiles, BK=64, swizzled LDS + XCD block swizzle --------

__global__ __launch_bounds__(256, 3) void gemm_qkv_kernel(
    const unsigned short* __restrict__ xb,
    const unsigned short* __restrict__ wqt, const unsigned short* __restrict__ wkt,
    const unsigned short* __restrict__ wvt,
    unsigned short* __restrict__ Qb, unsigned short* __restrict__ Kb,
    unsigned short* __restrict__ Vtb)
{
    __shared__ unsigned short As[128 * 64];
    __shared__ unsigned short Bs[128 * 64];
    const int t = threadIdx.x, lane = t & 63, wid = t >> 6;
    const int wr = wid >> 1, wc = wid & 1;
    const int l15 = lane & 15, l4 = lane >> 4;

    const int orig = blockIdx.x;
    const int wg = (orig & 7) * 96 + (orig >> 3);
    const int z = wg >> 8;
    const int rem = wg & 255;
    const int m0 = (rem >> 3) * 128, n0 = (rem & 7) * 128;
    const unsigned short* Bt = (z == 0) ? wqt : (z == 1) ? wkt : wvt;

    const int srow = t >> 3;
    const int srcoff = (((t & 7) ^ (srow & 7)) << 3);
    const unsigned short* Ab = xb + (size_t)(m0 + srow) * D_MODEL + srcoff;
    const unsigned short* Bb = Bt + (size_t)(n0 + srow) * D_MODEL + srcoff;
    const int ldsoff = t * 8;
    const int rsw = l15 & 7;

    f32x4 acc[4][4];
#pragma unroll
    for (int m = 0; m < 4; ++m)
#pragma unroll
        for (int n = 0; n < 4; ++n) acc[m][n] = (f32x4){0.f, 0.f, 0.f, 0.f};

    for (int k0 = 0; k0 < D_MODEL; k0 += 64) {
        __syncthreads();
#pragma unroll
        for (int i = 0; i < 4; ++i) {
            GLOAD_LDS16(Ab + (size_t)(i * 32) * D_MODEL + k0, &As[i * 2048 + ldsoff]);
            GLOAD_LDS16(Bb + (size_t)(i * 32) * D_MODEL + k0, &Bs[i * 2048 + ldsoff]);
        }
        __syncthreads();

#pragma unroll
        for (int ks = 0; ks < 2; ++ks) {
            const int csl = ks * 4 + l4;
            s16x8 af[4], bfr[4];
#pragma unroll
            for (int m = 0; m < 4; ++m)
                af[m] = *reinterpret_cast<const s16x8*>(
                    &As[(wr * 64 + m * 16 + l15) * 64 + ((csl ^ rsw) << 3)]);
#pragma unroll
            for (int n = 0; n < 4; ++n)
                bfr[n] = *reinterpret_cast<const s16x8*>(
                    &Bs[(wc * 64 + n * 16 + l15) * 64 + ((csl ^ rsw) << 3)]);
            __builtin_amdgcn_s_setprio(1);
#pragma unroll
            for (int m = 0; m < 4; ++m)
#pragma unroll
                for (int n = 0; n < 4; ++n)
                    acc[m][n] = __builtin_amdgcn_mfma_f32_16x16x32_bf16(af[m], bfr[n], acc[m][n], 0, 0, 0);
            __builtin_amdgcn_s_setprio(0);
        }
    }

    const int rb = m0 + wr * 64, cb = n0 + wc * 64;
    if (z == 2) {
#pragma unroll
        for (int m = 0; m < 4; ++m) {
            int row = rb + m * 16 + l4 * 4;
            int b = row >> 11, s = row & 2047;
#pragma unroll
            for (int n = 0; n < 4; ++n) {
                int col = cb + n * 16 + l15;
                int h = col >> 6, dk = col & 63;
                u16x4 o;
                o.x = f2bf(acc[m][n][0]); o.y = f2bf(acc[m][n][1]);
                o.z = f2bf(acc[m][n][2]); o.w = f2bf(acc[m][n][3]);
                *reinterpret_cast<u16x4*>(&Vtb[(((b * N_HEAD + h) * D_HEAD + dk) << 11) + s]) = o;
            }
        }
    } else {
        unsigned short* C = (z == 0) ? Qb : Kb;
        const float alpha = (z == 0) ? 0.18033688011112042f : 1.0f;  // (1/8)*log2(e)
#pragma unroll
        for (int m = 0; m < 4; ++m)
#pragma unroll
            for (int n = 0; n < 4; ++n)
#pragma unroll
                for (int r = 0; r < 4; ++r)
                    C[(rb + m * 16 + l4 * 4 + r) * D_MODEL + cb + n * 16 + l15] =
                        f2bf(acc[m][n][r] * alpha);
    }
}

// ---------------- gemm_out: 128x64 tiles, BK=64, swizzled LDS (r13 version, fusion REVERTED)

__global__ __launch_bounds__(256, 3) void gemm_out_kernel(
    const unsigned short* __restrict__ attnb, const unsigned short* __restrict__ wot,
    float* __restrict__ out)
{
    __shared__ unsigned short As[128 * 64];
    __shared__ unsigned short Bs[64 * 64];
    const int t = threadIdx.x, lane = t & 63, wid = t >> 6;
    const int wr = wid >> 1, wc = wid & 1;
    const int l15 = lane & 15, l4 = lane >> 4;

    const int orig = blockIdx.x;
    const int wg = (orig & 7) * 64 + (orig >> 3);
    const int m0 = (wg >> 4) * 128, n0 = (wg & 15) * 64;

    const int srow = t >> 3;
    const int srcoff = (((t & 7) ^ (srow & 7)) << 3);
    const unsigned short* Ab = attnb + (size_t)(m0 + srow) * D_MODEL + srcoff;
    const unsigned short* Bb = wot + (size_t)(n0 + srow) * D_MODEL + srcoff;
    const int ldsoff = t * 8;
    const int rsw = l15 & 7;

    f32x4 acc[4][2];
#pragma unroll
    for (int m = 0; m < 4; ++m)
#pragma unroll
        for (int n = 0; n < 2; ++n) acc[m][n] = (f32x4){0.f, 0.f, 0.f, 0.f};

    for (int k0 = 0; k0 < D_MODEL; k0 += 64) {
        __syncthreads();
#pragma unroll
        for (int i = 0; i < 4; ++i)
            GLOAD_LDS16(Ab + (size_t)(i * 32) * D_MODEL + k0, &As[i * 2048 + ldsoff]);
#pragma unroll
        for (int i = 0; i < 2; ++i)
            GLOAD_LDS16(Bb + (size_t)(i * 32) * D_MODEL + k0, &Bs[i * 2048 + ldsoff]);
        __syncthreads();

#pragma unroll
        for (int ks = 0; ks < 2; ++ks) {
            const int csl = ks * 4 + l4;
            s16x8 af[4], bfr[2];
#pragma unroll
            for (int m = 0; m < 4; ++m)
                af[m] = *reinterpret_cast<const s16x8*>(
                    &As[(wr * 64 + m * 16 + l15) * 64 + ((csl ^ rsw) << 3)]);
#pragma unroll
            for (int n = 0; n < 2; ++n)
                bfr[n] = *reinterpret_cast<const s16x8*>(
                    &Bs[(wc * 32 + n * 16 + l15) * 64 + ((csl ^ rsw) << 3)]);
            __builtin_amdgcn_s_setprio(1);
#pragma unroll
            for (int m = 0; m < 4; ++m)
#pragma unroll
                for (int n = 0; n < 2; ++n)
                    acc[m][n] = __builtin_amdgcn_mfma_f32_16x16x32_bf16(af[m], bfr[n], acc[m][n], 0, 0, 0);
            __builtin_amdgcn_s_setprio(0);
        }
    }

    const int rb = m0 + wr * 64, cb = n0 + wc * 32;
#pragma unroll
    for (int m = 0; m < 4; ++m)
#pragma unroll
        for (int n = 0; n < 2; ++n)
#pragma unroll
            for (int r = 0; r < 4; ++r)
                out[(rb + m * 16 + l4 * 4 + r) * D_MODEL + cb + n * 16 + l15] = acc[m][n][r];
}

// ---------------- flash attention v10: v8 + MFMA row-sum (kept from r14) ------------------

__global__ __launch_bounds__(256, 4) void attn_kernel(
    const unsigned short* __restrict__ Qb, const unsigned short* __restrict__ Kb,
    const unsigned short* __restrict__ Vtb, unsigned short* __restrict__ Ob,
    unsigned short* __restrict__ Opart, float* __restrict__ larr)
{
    __shared__ unsigned short SMEM[8192];       // K dbuf [2][4096]
    __shared__ unsigned short SMEMV[8192];      // V dbuf [2][4096]

    const int t = threadIdx.x;
    const int lane = t & 63, wid = t >> 6;      // 4 waves
    const int l31 = lane & 31, l5 = lane >> 5;

    const int bid = blockIdx.x;                 // 0..959
    const int type = bid >> 5, bh = bid & 31;
    const int s = T_S[type], c = T_C[type];
    const int ta = c * 12;
    const int tbf = 2 * (s + 1);
    const int tb = (ta + 12 < tbf) ? ta + 12 : tbf;
    const bool split = (s >= 6);
    const int slot = bh * 24 + ((s < 12) ? (s - 6) * 2 + c : 12 + (s - 12) * 3 + c);

    const int b = bh >> 4, h = bh & 15;
    const int q0 = s << 7;
    const int qw = q0 + wid * 32;
    const int qrow = qw + l31;

    s16x8 qf[4];
#pragma unroll
    for (int ks = 0; ks < 4; ++ks)
        qf[ks] = *reinterpret_cast<const s16x8*>(
            &Qb[(size_t)(b * SEQ + qrow) * D_MODEL + h * D_HEAD + ks * 16 + l5 * 8]);

    const short oneb = (short)0x3F80;           // bf16 1.0
    const s16x8 onesf = {oneb, oneb, oneb, oneb, oneb, oneb, oneb, oneb};

    f32x16 oacc[2], lacc;
#pragma unroll
    for (int d = 0; d < 2; ++d)
#pragma unroll
        for (int r = 0; r < 16; ++r) oacc[d][r] = 0.f;
#pragma unroll
    for (int r = 0; r < 16; ++r) lacc[r] = 0.f;

    const int stK = (wid & 1) * 32;
    const int srow = lane >> 3;
    const int scol = ((lane & 7) ^ srow) * 8;
    const unsigned short* kgb = Kb + (size_t)(b * SEQ + stK + srow) * D_MODEL + h * D_HEAD + scol;
    const unsigned short* vgb = Vtb + ((size_t)(bh * D_HEAD + stK + srow) << 11) + scol;
    const int swz = (l31 & 7);

#define STAGE(bufidx, kvbase) do { \
    if (wid < 2) { \
        const unsigned short* kg = kgb + (size_t)(kvbase) * D_MODEL; \
        _Pragma("unroll") \
        for (int i_ = 0; i_ < 4; ++i_) \
            GLOAD_LDS16(kg + (size_t)(i_ * 8) * D_MODEL, &SMEM[(bufidx) * 4096 + (stK + i_ * 8) * 64]); \
    } else { \
        const unsigned short* vg = vgb + (kvbase); \
        _Pragma("unroll") \
        for (int i_ = 0; i_ < 4; ++i_) \
            GLOAD_LDS16(vg + ((size_t)(i_ * 8) << 11), &SMEMV[(bufidx) * 4096 + (stK + i_ * 8) * 64]); \
    } } while (0)

    STAGE(0, ta * 64);

    for (int ti = ta; ti < tb; ++ti) {
        const int cur = (ti - ta) & 1;
        const int kv0 = ti * 64;
        __builtin_amdgcn_sched_barrier(0);
        asm volatile("s_waitcnt vmcnt(0)" ::: "memory");
        __builtin_amdgcn_s_barrier();
        if (ti + 1 < tb) STAGE(cur ^ 1, (ti + 1) * 64);
        __builtin_amdgcn_sched_barrier(0);

        if (kv0 > qw + 31) continue;

        const unsigned short* KsC = &SMEM[cur * 4096];
        const unsigned short* VsC = &SMEMV[cur * 4096];

        f32x16 sacc[2];
#pragma unroll
        for (int kvsub = 0; kvsub < 2; ++kvsub) {
            const bool active = (kv0 + kvsub * 32 <= qw + 31);
            if (active) {
#pragma unroll
                for (int r = 0; r < 16; ++r) sacc[kvsub][r] = -8.0f;
                __builtin_amdgcn_s_setprio(1);
#pragma unroll
                for (int ks = 0; ks < 4; ++ks) {
                    s16x8 kf = *reinterpret_cast<const s16x8*>(
                        &KsC[(kvsub * 32 + l31) * 64 + (((2 * ks + l5) ^ swz) * 8)]);
                    sacc[kvsub] = __builtin_amdgcn_mfma_f32_32x32x16_bf16(kf, qf[ks], sacc[kvsub], 0, 0, 0);
                }
                __builtin_amdgcn_s_setprio(0);
                if (kv0 + kvsub * 32 + 31 > qw) {
                    int kvbase = kv0 + kvsub * 32 + 4 * l5;
#pragma unroll
                    for (int r = 0; r < 16; ++r) {
                        int kvg = kvbase + (r & 3) + 8 * (r >> 2);
                        sacc[kvsub][r] = (kvg > qrow) ? -1e30f : sacc[kvsub][r];
                    }
                }
#pragma unroll
                for (int r = 0; r < 16; ++r) sacc[kvsub][r] = EXP2(sacc[kvsub][r]);
            } else {
#pragma unroll
                for (int r = 0; r < 16; ++r) sacc[kvsub][r] = 0.f;
            }
        }

        // ---- P -> bf16 (cvt_pk + permlane32_swap) + PV + l-accum on MFMA pipe ----
#pragma unroll
        for (int ks = 0; ks < 4; ++ks) {
            if (kv0 + (ks >> 1) * 32 > qw + 31) continue;
            const int kvsub = ks >> 1, bo = (ks & 1) * 8;
            unsigned a0 = cvtpk_bf16(sacc[kvsub][bo + 0], sacc[kvsub][bo + 1]);
            unsigned a1 = cvtpk_bf16(sacc[kvsub][bo + 2], sacc[kvsub][bo + 3]);
            unsigned a2 = cvtpk_bf16(sacc[kvsub][bo + 4], sacc[kvsub][bo + 5]);
            unsigned a3 = cvtpk_bf16(sacc[kvsub][bo + 6], sacc[kvsub][bo + 7]);
            asm volatile("v_permlane32_swap_b32 %0, %1" : "+v"(a0), "+v"(a2));
            asm volatile("v_permlane32_swap_b32 %0, %1" : "+v"(a1), "+v"(a3));
            u32x4 pw; pw.x = a0; pw.y = a1; pw.z = a2; pw.w = a3;
            s16x8 pf = __builtin_bit_cast(s16x8, pw);
            __builtin_amdgcn_s_setprio(1);
            lacc = __builtin_amdgcn_mfma_f32_32x32x16_bf16(onesf, pf, lacc, 0, 0, 0);
#pragma unroll
            for (int dsub = 0; dsub < 2; ++dsub) {
                s16x8 vf = *reinterpret_cast<const s16x8*>(
                    &VsC[(dsub * 32 + l31) * 64 + (((2 * ks + l5) ^ swz) * 8)]);
                oacc[dsub] = __builtin_amdgcn_mfma_f32_32x32x16_bf16(vf, pf, oacc[dsub], 0, 0, 0);
            }
            __builtin_amdgcn_s_setprio(0);
        }
    }
    __syncthreads();

    const float lrun = lacc[0];                 // all rows identical = sum_kv P[kv][q=lane&31]
    float inv = split ? 1.0f : (1.0f / lrun);
    const int orow = wid * 32 + l31;
#pragma unroll
    for (int dsub = 0; dsub < 2; ++dsub)
#pragma unroll
        for (int a = 0; a < 4; ++a) {
            unsigned w0 = cvtpk_bf16(oacc[dsub][4 * a + 0] * inv, oacc[dsub][4 * a + 1] * inv);
            unsigned w1 = cvtpk_bf16(oacc[dsub][4 * a + 2] * inv, oacc[dsub][4 * a + 3] * inv);
            int slt = (4 * dsub + a) ^ (orow & 7);
            uint2 pr; pr.x = w0; pr.y = w1;
            *reinterpret_cast<uint2*>(&SMEM[orow * 64 + slt * 8 + l5 * 4]) = pr;
        }
    __syncthreads();
    if (split) {
        unsigned short* Op = Opart + (size_t)slot * 8192;
#pragma unroll
        for (int i = 0; i < 4; ++i) {
            int g = i * 256 + t;
            int row = g >> 3, c16 = g & 7;
            int cs = (c16 ^ (row & 7)) * 8;
            *reinterpret_cast<s16x8*>(&Op[row * 64 + c16 * 8]) =
                *reinterpret_cast<const s16x8*>(&SMEM[row * 64 + cs]);
        }
        if (l5 == 0) larr[slot * 128 + orow] = lrun;
    } else {
#pragma unroll
        for (int i = 0; i < 4; ++i) {
            int g = i * 256 + t;
            int row = g >> 3, c16 = g & 7;
            int cs = (c16 ^ (row & 7)) * 8;
            s16x8 v = *reinterpret_cast<const s16x8*>(&SMEM[row * 64 + cs]);
            *reinterpret_cast<s16x8*>(
                &Ob[(size_t)(b * SEQ + q0 + row) * D_MODEL + h * D_HEAD + c16 * 8]) = v;
        }
    }
#undef STAGE
}

// ---------------- combine: Ob = (sum partials) / (sum l) for strips s>=6 ----------------

__global__ __launch_bounds__(256) void combine_kernel(
    const unsigned short* __restrict__ Opart, const float* __restrict__ larr,
    unsigned short* __restrict__ Ob)
{
    const int u = blockIdx.x;                   // 0..319 = bh*10 + (s-6)
    const int bh = u / 10, s = (u % 10) + 6;
    const int b = bh >> 4, h = bh & 15;
    const int base = bh * 24;
    const int s0 = (s < 12) ? base + (s - 6) * 2 : base + 12 + (s - 12) * 3;
    const int n = (s < 12) ? 2 : 3;
    const int t = threadIdx.x;
#pragma unroll
    for (int i = 0; i < 4; ++i) {
        int g = i * 256 + t;
        int row = g >> 3, c8 = (g & 7) * 8;
        float lsum = larr[s0 * 128 + row] + larr[(s0 + 1) * 128 + row];
        if (n == 3) lsum += larr[(s0 + 2) * 128 + row];
        float inv = 1.0f / lsum;
        float acc[8];
        {
            s16x8 va = *reinterpret_cast<const s16x8*>(&Opart[(size_t)s0 * 8192 + row * 64 + c8]);
            s16x8 vb = *reinterpret_cast<const s16x8*>(&Opart[(size_t)(s0 + 1) * 8192 + row * 64 + c8]);
#pragma unroll
            for (int j = 0; j < 8; ++j)
                acc[j] = bf2f((unsigned short)va[j]) + bf2f((unsigned short)vb[j]);
            if (n == 3) {
                s16x8 vc = *reinterpret_cast<const s16x8*>(&Opart[(size_t)(s0 + 2) * 8192 + row * 64 + c8]);
#pragma unroll
                for (int j = 0; j < 8; ++j) acc[j] += bf2f((unsigned short)vc[j]);
            }
        }
        union { s16x8 v; unsigned short e[8]; } o;
#pragma unroll
        for (int j = 0; j < 8; ++j) o.e[j] = f2bf(acc[j] * inv);
        *reinterpret_cast<s16x8*>(
            &Ob[(size_t)(b * SEQ + s * 128 + row) * D_MODEL + h * D_HEAD + c8]) = o.v;
    }
}

// ---------------- launch ----------------

extern "C" void kernel_launch(void* const* d_in, const int* in_sizes, int n_in,
                              void* d_out, int out_size, void* d_ws, size_t ws_size,
                              hipStream_t stream) {
    (void)in_sizes; (void)n_in; (void)out_size; (void)ws_size;
    const float* x  = (const float*)d_in[0];
    const float* wq = (const float*)d_in[1];
    const float* wk = (const float*)d_in[2];
    const float* wv = (const float*)d_in[3];
    const float* wo = (const float*)d_in[4];
    float* out = (float*)d_out;

    char* ws = (char*)d_ws;
    unsigned short* xb  = (unsigned short*)(ws);
    unsigned short* wqt = (unsigned short*)(ws + (8u  << 20));
    unsigned short* wkt = (unsigned short*)(ws + (10u << 20));
    unsigned short* wvt = (unsigned short*)(ws + (12u << 20));
    unsigned short* wot = (unsigned short*)(ws + (14u << 20));
    unsigned short* Qb  = (unsigned short*)(ws + (16u << 20));
    unsigned short* Kb  = (unsigned short*)(ws + (24u << 20));
    unsigned short* Vtb = (unsigned short*)(ws + (32u << 20));
    unsigned short* Ob  = (unsigned short*)(ws + (40u << 20));
    unsigned short* Opart = xb;                       // 768 slots x 128x64 bf16 = 12 MB
    float*          larr  = (float*)wvt;              // 768 x 128 fp32 (dead after qkv)

    hipLaunchKernelGGL(cvt_all_kernel, dim3(5120), dim3(256), 0, stream,
                       x, xb, wq, wk, wv, wo, wqt, wkt, wvt, wot);

    hipLaunchKernelGGL(gemm_qkv_kernel, dim3(768), dim3(256), 0, stream,
                       xb, wqt, wkt, wvt, Qb, Kb, Vtb);
    hipLaunchKernelGGL(attn_kernel, dim3(960), dim3(256), 0, stream,
                       Qb, Kb, Vtb, Ob, Opart, larr);
    hipLaunchKernelGGL(combine_kernel, dim3(320), dim3(256), 0, stream, Opart, larr, Ob);
    hipLaunchKernelGGL(gemm_out_kernel, dim3(512), dim3(256), 0, stream, Ob, wot, out);
}

// Round 16
// 98.909 us; speedup vs baseline: 1.6255x; 1.0563x over previous
//
#include <hip/hip_runtime.h>
#include <hip/hip_bf16.h>

typedef short s16x8 __attribute__((ext_vector_type(8)));
typedef float f32x4 __attribute__((ext_vector_type(4)));
typedef float f32x16 __attribute__((ext_vector_type(16)));
typedef unsigned short u16x4 __attribute__((ext_vector_type(4)));
typedef unsigned int u32x4 __attribute__((ext_vector_type(4)));

#define D_MODEL 1024
#define N_HEAD  16
#define D_HEAD  64
#define SEQ     2048
#define NBATCH  2

#if __has_builtin(__builtin_amdgcn_exp2f)
#define EXP2(x) __builtin_amdgcn_exp2f(x)
#else
#define EXP2(x) exp2f(x)
#endif

#define GLOAD_LDS16(g, l) \
    __builtin_amdgcn_global_load_lds((const __attribute__((address_space(1))) void*)(g), \
                                     (__attribute__((address_space(3))) void*)(l), 16, 0, 0)

__device__ __forceinline__ unsigned short f2bf(float f) {
    union { float f; unsigned int u; } v; v.f = f;
    unsigned int r = v.u + 0x7FFFu + ((v.u >> 16) & 1u);
    return (unsigned short)(r >> 16);
}

__device__ __forceinline__ float bf2f(unsigned short u) {
    union { unsigned int u; float f; } v; v.u = ((unsigned int)u) << 16;
    return v.f;
}

__device__ __forceinline__ unsigned cvtpk_bf16(float lo, float hi) {
    unsigned r;
    asm("v_cvt_pk_bf16_f32 %0, %1, %2" : "=v"(r) : "v"(lo), "v"(hi));
    return r;
}

// item tables: 30 types, descending size (full-12 chunks first). s = strip, c = chunk idx.
__device__ const unsigned char T_S[30] = {5,6,7,8,9,10,11,11,12,12,13,13,14,14,15,15,
                                          4,10, 3,9,15, 2,8,14, 1,7,13, 0,6,12};
__device__ const unsigned char T_C[30] = {0,0,0,0,0,0,0,1,0,1,0,1,0,1,0,1,
                                          0,1, 0,1,2, 0,1,2, 0,1,2, 0,1,2};

// ---------------- fused conversion: x (4096 blocks) + 4 weights (1024 blocks) -------------

__global__ __launch_bounds__(256) void cvt_all_kernel(
    const float* __restrict__ x, unsigned short* __restrict__ xb,
    const float* __restrict__ w0, const float* __restrict__ w1,
    const float* __restrict__ w2, const float* __restrict__ w3,
    unsigned short* __restrict__ o0, unsigned short* __restrict__ o1,
    unsigned short* __restrict__ o2, unsigned short* __restrict__ o3)
{
    __shared__ unsigned short T[64][72];
    const int t = threadIdx.x;
    const int bid = blockIdx.x;
    if (bid < 4096) {
        int i = (bid * 256 + t) * 4;
        float4 v = *reinterpret_cast<const float4*>(x + i);
        u16x4 o;
        o.x = f2bf(v.x); o.y = f2bf(v.y); o.z = f2bf(v.z); o.w = f2bf(v.w);
        *reinterpret_cast<u16x4*>(xb + i) = o;
        return;
    }
    const int u = bid - 4096;
    const int z = u >> 8, tile = u & 255;
    const float* w = (z == 0) ? w0 : (z == 1) ? w1 : (z == 2) ? w2 : w3;
    unsigned short* wt = (z == 0) ? o0 : (z == 1) ? o1 : (z == 2) ? o2 : o3;
    const int k0 = (tile & 15) * 64, n0 = (tile >> 4) * 64;
#pragma unroll
    for (int i = 0; i < 4; ++i) {
        int k = (t >> 4) + i * 16;
        int n = (t & 15) * 4;
        float4 v = *reinterpret_cast<const float4*>(&w[(k0 + k) * 1024 + n0 + n]);
        T[n + 0][k] = f2bf(v.x); T[n + 1][k] = f2bf(v.y);
        T[n + 2][k] = f2bf(v.z); T[n + 3][k] = f2bf(v.w);
    }
    __syncthreads();
#pragma unroll
    for (int i = 0; i < 2; ++i) {
        int n = (t >> 3) + i * 32;
        int kc = (t & 7) * 8;
        *reinterpret_cast<s16x8*>(&wt[(n0 + n) * 1024 + k0 + kc]) =
            *reinterpret_cast<const s16x8*>(&T[n][kc]);
    }
}

// ---------------- gemm_qkv: 128x128 tiles, BK=64, swizzled LDS + XCD block swizzle --------

__global__ __launch_bounds__(256, 3) void gemm_qkv_kernel(
    const unsigned short* __restrict__ xb,
    const unsigned short* __restrict__ wqt, const unsigned short* __restrict__ wkt,
    const unsigned short* __restrict__ wvt,
    unsigned short* __restrict__ Qb, unsigned short* __restrict__ Kb,
    unsigned short* __restrict__ Vtb)
{
    __shared__ unsigned short As[128 * 64];
    __shared__ unsigned short Bs[128 * 64];
    const int t = threadIdx.x, lane = t & 63, wid = t >> 6;
    const int wr = wid >> 1, wc = wid & 1;
    const int l15 = lane & 15, l4 = lane >> 4;

    const int orig = blockIdx.x;
    const int wg = (orig & 7) * 96 + (orig >> 3);
    const int z = wg >> 8;
    const int rem = wg & 255;
    const int m0 = (rem >> 3) * 128, n0 = (rem & 7) * 128;
    const unsigned short* Bt = (z == 0) ? wqt : (z == 1) ? wkt : wvt;

    const int srow = t >> 3;
    const int srcoff = (((t & 7) ^ (srow & 7)) << 3);
    const unsigned short* Ab = xb + (size_t)(m0 + srow) * D_MODEL + srcoff;
    const unsigned short* Bb = Bt + (size_t)(n0 + srow) * D_MODEL + srcoff;
    const int ldsoff = t * 8;
    const int rsw = l15 & 7;

    f32x4 acc[4][4];
#pragma unroll
    for (int m = 0; m < 4; ++m)
#pragma unroll
        for (int n = 0; n < 4; ++n) acc[m][n] = (f32x4){0.f, 0.f, 0.f, 0.f};

    for (int k0 = 0; k0 < D_MODEL; k0 += 64) {
        __syncthreads();
#pragma unroll
        for (int i = 0; i < 4; ++i) {
            GLOAD_LDS16(Ab + (size_t)(i * 32) * D_MODEL + k0, &As[i * 2048 + ldsoff]);
            GLOAD_LDS16(Bb + (size_t)(i * 32) * D_MODEL + k0, &Bs[i * 2048 + ldsoff]);
        }
        __syncthreads();

#pragma unroll
        for (int ks = 0; ks < 2; ++ks) {
            const int csl = ks * 4 + l4;
            s16x8 af[4], bfr[4];
#pragma unroll
            for (int m = 0; m < 4; ++m)
                af[m] = *reinterpret_cast<const s16x8*>(
                    &As[(wr * 64 + m * 16 + l15) * 64 + ((csl ^ rsw) << 3)]);
#pragma unroll
            for (int n = 0; n < 4; ++n)
                bfr[n] = *reinterpret_cast<const s16x8*>(
                    &Bs[(wc * 64 + n * 16 + l15) * 64 + ((csl ^ rsw) << 3)]);
            __builtin_amdgcn_s_setprio(1);
#pragma unroll
            for (int m = 0; m < 4; ++m)
#pragma unroll
                for (int n = 0; n < 4; ++n)
                    acc[m][n] = __builtin_amdgcn_mfma_f32_16x16x32_bf16(af[m], bfr[n], acc[m][n], 0, 0, 0);
            __builtin_amdgcn_s_setprio(0);
        }
    }

    const int rb = m0 + wr * 64, cb = n0 + wc * 64;
    if (z == 2) {
#pragma unroll
        for (int m = 0; m < 4; ++m) {
            int row = rb + m * 16 + l4 * 4;
            int b = row >> 11, s = row & 2047;
#pragma unroll
            for (int n = 0; n < 4; ++n) {
                int col = cb + n * 16 + l15;
                int h = col >> 6, dk = col & 63;
                u16x4 o;
                o.x = f2bf(acc[m][n][0]); o.y = f2bf(acc[m][n][1]);
                o.z = f2bf(acc[m][n][2]); o.w = f2bf(acc[m][n][3]);
                *reinterpret_cast<u16x4*>(&Vtb[(((b * N_HEAD + h) * D_HEAD + dk) << 11) + s]) = o;
            }
        }
    } else {
        unsigned short* C = (z == 0) ? Qb : Kb;
        const float alpha = (z == 0) ? 0.18033688011112042f : 1.0f;  // (1/8)*log2(e)
#pragma unroll
        for (int m = 0; m < 4; ++m)
#pragma unroll
            for (int n = 0; n < 4; ++n)
#pragma unroll
                for (int r = 0; r < 4; ++r)
                    C[(rb + m * 16 + l4 * 4 + r) * D_MODEL + cb + n * 16 + l15] =
                        f2bf(acc[m][n][r] * alpha);
    }
}

// ---------------- gemm_out: 128x64 tiles, BK=64, swizzled LDS (r13 version) ---------------

__global__ __launch_bounds__(256, 3) void gemm_out_kernel(
    const unsigned short* __restrict__ attnb, const unsigned short* __restrict__ wot,
    float* __restrict__ out)
{
    __shared__ unsigned short As[128 * 64];
    __shared__ unsigned short Bs[64 * 64];
    const int t = threadIdx.x, lane = t & 63, wid = t >> 6;
    const int wr = wid >> 1, wc = wid & 1;
    const int l15 = lane & 15, l4 = lane >> 4;

    const int orig = blockIdx.x;
    const int wg = (orig & 7) * 64 + (orig >> 3);
    const int m0 = (wg >> 4) * 128, n0 = (wg & 15) * 64;

    const int srow = t >> 3;
    const int srcoff = (((t & 7) ^ (srow & 7)) << 3);
    const unsigned short* Ab = attnb + (size_t)(m0 + srow) * D_MODEL + srcoff;
    const unsigned short* Bb = wot + (size_t)(n0 + srow) * D_MODEL + srcoff;
    const int ldsoff = t * 8;
    const int rsw = l15 & 7;

    f32x4 acc[4][2];
#pragma unroll
    for (int m = 0; m < 4; ++m)
#pragma unroll
        for (int n = 0; n < 2; ++n) acc[m][n] = (f32x4){0.f, 0.f, 0.f, 0.f};

    for (int k0 = 0; k0 < D_MODEL; k0 += 64) {
        __syncthreads();
#pragma unroll
        for (int i = 0; i < 4; ++i)
            GLOAD_LDS16(Ab + (size_t)(i * 32) * D_MODEL + k0, &As[i * 2048 + ldsoff]);
#pragma unroll
        for (int i = 0; i < 2; ++i)
            GLOAD_LDS16(Bb + (size_t)(i * 32) * D_MODEL + k0, &Bs[i * 2048 + ldsoff]);
        __syncthreads();

#pragma unroll
        for (int ks = 0; ks < 2; ++ks) {
            const int csl = ks * 4 + l4;
            s16x8 af[4], bfr[2];
#pragma unroll
            for (int m = 0; m < 4; ++m)
                af[m] = *reinterpret_cast<const s16x8*>(
                    &As[(wr * 64 + m * 16 + l15) * 64 + ((csl ^ rsw) << 3)]);
#pragma unroll
            for (int n = 0; n < 2; ++n)
                bfr[n] = *reinterpret_cast<const s16x8*>(
                    &Bs[(wc * 32 + n * 16 + l15) * 64 + ((csl ^ rsw) << 3)]);
            __builtin_amdgcn_s_setprio(1);
#pragma unroll
            for (int m = 0; m < 4; ++m)
#pragma unroll
                for (int n = 0; n < 2; ++n)
                    acc[m][n] = __builtin_amdgcn_mfma_f32_16x16x32_bf16(af[m], bfr[n], acc[m][n], 0, 0, 0);
            __builtin_amdgcn_s_setprio(0);
        }
    }

    const int rb = m0 + wr * 64, cb = n0 + wc * 32;
#pragma unroll
    for (int m = 0; m < 4; ++m)
#pragma unroll
        for (int n = 0; n < 2; ++n)
#pragma unroll
            for (int r = 0; r < 4; ++r)
                out[(rb + m * 16 + l4 * 4 + r) * D_MODEL + cb + n * 16 + l15] = acc[m][n][r];
}

// ---------------- flash attention v11: v8 + DEFERRED l-reduction --------------------------
// Per tile: 16 independent lsum[r] += adds (no tree, no shuffle on critical path).
// Tree + cross-half shuffle run ONCE in the epilogue (valid since fixed-base softmax
// has no per-tile rescale). v10's lacc-MFMA reverted (serial MFMA chain regressed 8us).

__global__ __launch_bounds__(256, 4) void attn_kernel(
    const unsigned short* __restrict__ Qb, const unsigned short* __restrict__ Kb,
    const unsigned short* __restrict__ Vtb, unsigned short* __restrict__ Ob,
    unsigned short* __restrict__ Opart, float* __restrict__ larr)
{
    __shared__ unsigned short SMEM[8192];       // K dbuf [2][4096]
    __shared__ unsigned short SMEMV[8192];      // V dbuf [2][4096]

    const int t = threadIdx.x;
    const int lane = t & 63, wid = t >> 6;      // 4 waves
    const int l31 = lane & 31, l5 = lane >> 5;

    const int bid = blockIdx.x;                 // 0..959
    const int type = bid >> 5, bh = bid & 31;
    const int s = T_S[type], c = T_C[type];
    const int ta = c * 12;
    const int tbf = 2 * (s + 1);
    const int tb = (ta + 12 < tbf) ? ta + 12 : tbf;
    const bool split = (s >= 6);
    const int slot = bh * 24 + ((s < 12) ? (s - 6) * 2 + c : 12 + (s - 12) * 3 + c);

    const int b = bh >> 4, h = bh & 15;
    const int q0 = s << 7;
    const int qw = q0 + wid * 32;
    const int qrow = qw + l31;

    s16x8 qf[4];
#pragma unroll
    for (int ks = 0; ks < 4; ++ks)
        qf[ks] = *reinterpret_cast<const s16x8*>(
            &Qb[(size_t)(b * SEQ + qrow) * D_MODEL + h * D_HEAD + ks * 16 + l5 * 8]);

    f32x16 oacc[2], lsum;
#pragma unroll
    for (int d = 0; d < 2; ++d)
#pragma unroll
        for (int r = 0; r < 16; ++r) oacc[d][r] = 0.f;
#pragma unroll
    for (int r = 0; r < 16; ++r) lsum[r] = 0.f;

    const int stK = (wid & 1) * 32;
    const int srow = lane >> 3;
    const int scol = ((lane & 7) ^ srow) * 8;
    const unsigned short* kgb = Kb + (size_t)(b * SEQ + stK + srow) * D_MODEL + h * D_HEAD + scol;
    const unsigned short* vgb = Vtb + ((size_t)(bh * D_HEAD + stK + srow) << 11) + scol;
    const int swz = (l31 & 7);

#define STAGE(bufidx, kvbase) do { \
    if (wid < 2) { \
        const unsigned short* kg = kgb + (size_t)(kvbase) * D_MODEL; \
        _Pragma("unroll") \
        for (int i_ = 0; i_ < 4; ++i_) \
            GLOAD_LDS16(kg + (size_t)(i_ * 8) * D_MODEL, &SMEM[(bufidx) * 4096 + (stK + i_ * 8) * 64]); \
    } else { \
        const unsigned short* vg = vgb + (kvbase); \
        _Pragma("unroll") \
        for (int i_ = 0; i_ < 4; ++i_) \
            GLOAD_LDS16(vg + ((size_t)(i_ * 8) << 11), &SMEMV[(bufidx) * 4096 + (stK + i_ * 8) * 64]); \
    } } while (0)

    STAGE(0, ta * 64);

    for (int ti = ta; ti < tb; ++ti) {
        const int cur = (ti - ta) & 1;
        const int kv0 = ti * 64;
        __builtin_amdgcn_sched_barrier(0);
        asm volatile("s_waitcnt vmcnt(0)" ::: "memory");
        __builtin_amdgcn_s_barrier();
        if (ti + 1 < tb) STAGE(cur ^ 1, (ti + 1) * 64);
        __builtin_amdgcn_sched_barrier(0);

        if (kv0 > qw + 31) continue;

        const unsigned short* KsC = &SMEM[cur * 4096];
        const unsigned short* VsC = &SMEMV[cur * 4096];

        f32x16 sacc[2];
#pragma unroll
        for (int kvsub = 0; kvsub < 2; ++kvsub) {
            const bool active = (kv0 + kvsub * 32 <= qw + 31);
            if (active) {
#pragma unroll
                for (int r = 0; r < 16; ++r) sacc[kvsub][r] = -8.0f;
                __builtin_amdgcn_s_setprio(1);
#pragma unroll
                for (int ks = 0; ks < 4; ++ks) {
                    s16x8 kf = *reinterpret_cast<const s16x8*>(
                        &KsC[(kvsub * 32 + l31) * 64 + (((2 * ks + l5) ^ swz) * 8)]);
                    sacc[kvsub] = __builtin_amdgcn_mfma_f32_32x32x16_bf16(kf, qf[ks], sacc[kvsub], 0, 0, 0);
                }
                __builtin_amdgcn_s_setprio(0);
                if (kv0 + kvsub * 32 + 31 > qw) {
                    int kvbase = kv0 + kvsub * 32 + 4 * l5;
#pragma unroll
                    for (int r = 0; r < 16; ++r) {
                        int kvg = kvbase + (r & 3) + 8 * (r >> 2);
                        sacc[kvsub][r] = (kvg > qrow) ? -1e30f : sacc[kvsub][r];
                    }
                }
#pragma unroll
                for (int r = 0; r < 16; ++r) sacc[kvsub][r] = EXP2(sacc[kvsub][r]);
            } else {
#pragma unroll
                for (int r = 0; r < 16; ++r) sacc[kvsub][r] = 0.f;
            }
        }

        // ---- deferred l: 16 independent accumulates, no tree/shuffle in-loop ----
#pragma unroll
        for (int r = 0; r < 16; ++r) lsum[r] += sacc[0][r] + sacc[1][r];

        // ---- P -> bf16 (cvt_pk + permlane32_swap) + PV ----
#pragma unroll
        for (int ks = 0; ks < 4; ++ks) {
            if (kv0 + (ks >> 1) * 32 > qw + 31) continue;
            const int kvsub = ks >> 1, bo = (ks & 1) * 8;
            unsigned a0 = cvtpk_bf16(sacc[kvsub][bo + 0], sacc[kvsub][bo + 1]);
            unsigned a1 = cvtpk_bf16(sacc[kvsub][bo + 2], sacc[kvsub][bo + 3]);
            unsigned a2 = cvtpk_bf16(sacc[kvsub][bo + 4], sacc[kvsub][bo + 5]);
            unsigned a3 = cvtpk_bf16(sacc[kvsub][bo + 6], sacc[kvsub][bo + 7]);
            asm volatile("v_permlane32_swap_b32 %0, %1" : "+v"(a0), "+v"(a2));
            asm volatile("v_permlane32_swap_b32 %0, %1" : "+v"(a1), "+v"(a3));
            u32x4 pw; pw.x = a0; pw.y = a1; pw.z = a2; pw.w = a3;
            s16x8 pf = __builtin_bit_cast(s16x8, pw);
            __builtin_amdgcn_s_setprio(1);
#pragma unroll
            for (int dsub = 0; dsub < 2; ++dsub) {
                s16x8 vf = *reinterpret_cast<const s16x8*>(
                    &VsC[(dsub * 32 + l31) * 64 + (((2 * ks + l5) ^ swz) * 8)]);
                oacc[dsub] = __builtin_amdgcn_mfma_f32_32x32x16_bf16(vf, pf, oacc[dsub], 0, 0, 0);
            }
            __builtin_amdgcn_s_setprio(0);
        }
    }
    __syncthreads();

    // ---- one-time l reduction (tree + cross-half shuffle) ----
    float red[16];
#pragma unroll
    for (int r = 0; r < 16; ++r) red[r] = lsum[r];
#pragma unroll
    for (int sj = 8; sj >= 1; sj >>= 1)
#pragma unroll
        for (int r = 0; r < 8; ++r)
            if (r < sj) red[r] += red[r + sj];
    const float lrun = red[0] + __shfl_xor(red[0], 32);

    float inv = split ? 1.0f : (1.0f / lrun);
    const int orow = wid * 32 + l31;
#pragma unroll
    for (int dsub = 0; dsub < 2; ++dsub)
#pragma unroll
        for (int a = 0; a < 4; ++a) {
            unsigned w0 = cvtpk_bf16(oacc[dsub][4 * a + 0] * inv, oacc[dsub][4 * a + 1] * inv);
            unsigned w1 = cvtpk_bf16(oacc[dsub][4 * a + 2] * inv, oacc[dsub][4 * a + 3] * inv);
            int slt = (4 * dsub + a) ^ (orow & 7);
            uint2 pr; pr.x = w0; pr.y = w1;
            *reinterpret_cast<uint2*>(&SMEM[orow * 64 + slt * 8 + l5 * 4]) = pr;
        }
    __syncthreads();
    if (split) {
        unsigned short* Op = Opart + (size_t)slot * 8192;
#pragma unroll
        for (int i = 0; i < 4; ++i) {
            int g = i * 256 + t;
            int row = g >> 3, c16 = g & 7;
            int cs = (c16 ^ (row & 7)) * 8;
            *reinterpret_cast<s16x8*>(&Op[row * 64 + c16 * 8]) =
                *reinterpret_cast<const s16x8*>(&SMEM[row * 64 + cs]);
        }
        if (l5 == 0) larr[slot * 128 + orow] = lrun;
    } else {
#pragma unroll
        for (int i = 0; i < 4; ++i) {
            int g = i * 256 + t;
            int row = g >> 3, c16 = g & 7;
            int cs = (c16 ^ (row & 7)) * 8;
            s16x8 v = *reinterpret_cast<const s16x8*>(&SMEM[row * 64 + cs]);
            *reinterpret_cast<s16x8*>(
                &Ob[(size_t)(b * SEQ + q0 + row) * D_MODEL + h * D_HEAD + c16 * 8]) = v;
        }
    }
#undef STAGE
}

// ---------------- combine: Ob = (sum partials) / (sum l) for strips s>=6 ----------------

__global__ __launch_bounds__(256) void combine_kernel(
    const unsigned short* __restrict__ Opart, const float* __restrict__ larr,
    unsigned short* __restrict__ Ob)
{
    const int u = blockIdx.x;                   // 0..319 = bh*10 + (s-6)
    const int bh = u / 10, s = (u % 10) + 6;
    const int b = bh >> 4, h = bh & 15;
    const int base = bh * 24;
    const int s0 = (s < 12) ? base + (s - 6) * 2 : base + 12 + (s - 12) * 3;
    const int n = (s < 12) ? 2 : 3;
    const int t = threadIdx.x;
#pragma unroll
    for (int i = 0; i < 4; ++i) {
        int g = i * 256 + t;
        int row = g >> 3, c8 = (g & 7) * 8;
        float lsum = larr[s0 * 128 + row] + larr[(s0 + 1) * 128 + row];
        if (n == 3) lsum += larr[(s0 + 2) * 128 + row];
        float inv = 1.0f / lsum;
        float acc[8];
        {
            s16x8 va = *reinterpret_cast<const s16x8*>(&Opart[(size_t)s0 * 8192 + row * 64 + c8]);
            s16x8 vb = *reinterpret_cast<const s16x8*>(&Opart[(size_t)(s0 + 1) * 8192 + row * 64 + c8]);
#pragma unroll
            for (int j = 0; j < 8; ++j)
                acc[j] = bf2f((unsigned short)va[j]) + bf2f((unsigned short)vb[j]);
            if (n == 3) {
                s16x8 vc = *reinterpret_cast<const s16x8*>(&Opart[(size_t)(s0 + 2) * 8192 + row * 64 + c8]);
#pragma unroll
                for (int j = 0; j < 8; ++j) acc[j] += bf2f((unsigned short)vc[j]);
            }
        }
        union { s16x8 v; unsigned short e[8]; } o;
#pragma unroll
        for (int j = 0; j < 8; ++j) o.e[j] = f2bf(acc[j] * inv);
        *reinterpret_cast<s16x8*>(
            &Ob[(size_t)(b * SEQ + s * 128 + row) * D_MODEL + h * D_HEAD + c8]) = o.v;
    }
}

// ---------------- launch ----------------

extern "C" void kernel_launch(void* const* d_in, const int* in_sizes, int n_in,
                              void* d_out, int out_size, void* d_ws, size_t ws_size,
                              hipStream_t stream) {
    (void)in_sizes; (void)n_in; (void)out_size; (void)ws_size;
    const float* x  = (const float*)d_in[0];
    const float* wq = (const float*)d_in[1];
    const float* wk = (const float*)d_in[2];
    const float* wv = (const float*)d_in[3];
    const float* wo = (const float*)d_in[4];
    float* out = (float*)d_out;

    char* ws = (char*)d_ws;
    unsigned short* xb  = (unsigned short*)(ws);
    unsigned short* wqt = (unsigned short*)(ws + (8u  << 20));
    unsigned short* wkt = (unsigned short*)(ws + (10u << 20));
    unsigned short* wvt = (unsigned short*)(ws + (12u << 20));
    unsigned short* wot = (unsigned short*)(ws + (14u << 20));
    unsigned short* Qb  = (unsigned short*)(ws + (16u << 20));
    unsigned short* Kb  = (unsigned short*)(ws + (24u << 20));
    unsigned short* Vtb = (unsigned short*)(ws + (32u << 20));
    unsigned short* Ob  = (unsigned short*)(ws + (40u << 20));
    unsigned short* Opart = xb;                       // 768 slots x 128x64 bf16 = 12 MB
    float*          larr  = (float*)wvt;              // 768 x 128 fp32 (dead after qkv)

    hipLaunchKernelGGL(cvt_all_kernel, dim3(5120), dim3(256), 0, stream,
                       x, xb, wq, wk, wv, wo, wqt, wkt, wvt, wot);

    hipLaunchKernelGGL(gemm_qkv_kernel, dim3(768), dim3(256), 0, stream,
                       xb, wqt, wkt, wvt, Qb, Kb, Vtb);
    hipLaunchKernelGGL(attn_kernel, dim3(960), dim3(256), 0, stream,
                       Qb, Kb, Vtb, Ob, Opart, larr);
    hipLaunchKernelGGL(combine_kernel, dim3(320), dim3(256), 0, stream, Opart, larr, Ob);
    hipLaunchKernelGGL(gemm_out_kernel, dim3(512), dim3(256), 0, stream, Ob, wot, out);
}

// Round 17
// 97.238 us; speedup vs baseline: 1.6534x; 1.0172x over previous
//
#include <hip/hip_runtime.h>
#include <hip/hip_bf16.h>

typedef short s16x8 __attribute__((ext_vector_type(8)));
typedef float f32x4 __attribute__((ext_vector_type(4)));
typedef float f32x16 __attribute__((ext_vector_type(16)));
typedef unsigned short u16x4 __attribute__((ext_vector_type(4)));
typedef unsigned int u32x4 __attribute__((ext_vector_type(4)));

#define D_MODEL 1024
#define N_HEAD  16
#define D_HEAD  64
#define SEQ     2048
#define NBATCH  2

#if __has_builtin(__builtin_amdgcn_exp2f)
#define EXP2(x) __builtin_amdgcn_exp2f(x)
#else
#define EXP2(x) exp2f(x)
#endif

#define GLOAD_LDS16(g, l) \
    __builtin_amdgcn_global_load_lds((const __attribute__((address_space(1))) void*)(g), \
                                     (__attribute__((address_space(3))) void*)(l), 16, 0, 0)

__device__ __forceinline__ unsigned short f2bf(float f) {
    union { float f; unsigned int u; } v; v.f = f;
    unsigned int r = v.u + 0x7FFFu + ((v.u >> 16) & 1u);
    return (unsigned short)(r >> 16);
}

__device__ __forceinline__ float bf2f(unsigned short u) {
    union { unsigned int u; float f; } v; v.u = ((unsigned int)u) << 16;
    return v.f;
}

__device__ __forceinline__ unsigned cvtpk_bf16(float lo, float hi) {
    unsigned r;
    asm("v_cvt_pk_bf16_f32 %0, %1, %2" : "=v"(r) : "v"(lo), "v"(hi));
    return r;
}

// item tables: 30 types, descending size (full-12 chunks first). s = strip, c = chunk idx.
__device__ const unsigned char T_S[30] = {5,6,7,8,9,10,11,11,12,12,13,13,14,14,15,15,
                                          4,10, 3,9,15, 2,8,14, 1,7,13, 0,6,12};
__device__ const unsigned char T_C[30] = {0,0,0,0,0,0,0,1,0,1,0,1,0,1,0,1,
                                          0,1, 0,1,2, 0,1,2, 0,1,2, 0,1,2};

// ---------------- fused conversion: x (4096 blocks) + 4 weights (1024 blocks) -------------

__global__ __launch_bounds__(256) void cvt_all_kernel(
    const float* __restrict__ x, unsigned short* __restrict__ xb,
    const float* __restrict__ w0, const float* __restrict__ w1,
    const float* __restrict__ w2, const float* __restrict__ w3,
    unsigned short* __restrict__ o0, unsigned short* __restrict__ o1,
    unsigned short* __restrict__ o2, unsigned short* __restrict__ o3)
{
    __shared__ unsigned short T[64][72];
    const int t = threadIdx.x;
    const int bid = blockIdx.x;
    if (bid < 4096) {
        int i = (bid * 256 + t) * 4;
        float4 v = *reinterpret_cast<const float4*>(x + i);
        u16x4 o;
        o.x = f2bf(v.x); o.y = f2bf(v.y); o.z = f2bf(v.z); o.w = f2bf(v.w);
        *reinterpret_cast<u16x4*>(xb + i) = o;
        return;
    }
    const int u = bid - 4096;
    const int z = u >> 8, tile = u & 255;
    const float* w = (z == 0) ? w0 : (z == 1) ? w1 : (z == 2) ? w2 : w3;
    unsigned short* wt = (z == 0) ? o0 : (z == 1) ? o1 : (z == 2) ? o2 : o3;
    const int k0 = (tile & 15) * 64, n0 = (tile >> 4) * 64;
#pragma unroll
    for (int i = 0; i < 4; ++i) {
        int k = (t >> 4) + i * 16;
        int n = (t & 15) * 4;
        float4 v = *reinterpret_cast<const float4*>(&w[(k0 + k) * 1024 + n0 + n]);
        T[n + 0][k] = f2bf(v.x); T[n + 1][k] = f2bf(v.y);
        T[n + 2][k] = f2bf(v.z); T[n + 3][k] = f2bf(v.w);
    }
    __syncthreads();
#pragma unroll
    for (int i = 0; i < 2; ++i) {
        int n = (t >> 3) + i * 32;
        int kc = (t & 7) * 8;
        *reinterpret_cast<s16x8*>(&wt[(n0 + n) * 1024 + k0 + kc]) =
            *reinterpret_cast<const s16x8*>(&T[n][kc]);
    }
}

// ---------------- gemm_qkv: 128x128 tiles, BK=64, swizzled LDS + XCD block swizzle --------

__global__ __launch_bounds__(256, 3) void gemm_qkv_kernel(
    const unsigned short* __restrict__ xb,
    const unsigned short* __restrict__ wqt, const unsigned short* __restrict__ wkt,
    const unsigned short* __restrict__ wvt,
    unsigned short* __restrict__ Qb, unsigned short* __restrict__ Kb,
    unsigned short* __restrict__ Vtb)
{
    __shared__ unsigned short As[128 * 64];
    __shared__ unsigned short Bs[128 * 64];
    const int t = threadIdx.x, lane = t & 63, wid = t >> 6;
    const int wr = wid >> 1, wc = wid & 1;
    const int l15 = lane & 15, l4 = lane >> 4;

    const int orig = blockIdx.x;
    const int wg = (orig & 7) * 96 + (orig >> 3);
    const int z = wg >> 8;
    const int rem = wg & 255;
    const int m0 = (rem >> 3) * 128, n0 = (rem & 7) * 128;
    const unsigned short* Bt = (z == 0) ? wqt : (z == 1) ? wkt : wvt;

    const int srow = t >> 3;
    const int srcoff = (((t & 7) ^ (srow & 7)) << 3);
    const unsigned short* Ab = xb + (size_t)(m0 + srow) * D_MODEL + srcoff;
    const unsigned short* Bb = Bt + (size_t)(n0 + srow) * D_MODEL + srcoff;
    const int ldsoff = t * 8;
    const int rsw = l15 & 7;

    f32x4 acc[4][4];
#pragma unroll
    for (int m = 0; m < 4; ++m)
#pragma unroll
        for (int n = 0; n < 4; ++n) acc[m][n] = (f32x4){0.f, 0.f, 0.f, 0.f};

    for (int k0 = 0; k0 < D_MODEL; k0 += 64) {
        __syncthreads();
#pragma unroll
        for (int i = 0; i < 4; ++i) {
            GLOAD_LDS16(Ab + (size_t)(i * 32) * D_MODEL + k0, &As[i * 2048 + ldsoff]);
            GLOAD_LDS16(Bb + (size_t)(i * 32) * D_MODEL + k0, &Bs[i * 2048 + ldsoff]);
        }
        __syncthreads();

#pragma unroll
        for (int ks = 0; ks < 2; ++ks) {
            const int csl = ks * 4 + l4;
            s16x8 af[4], bfr[4];
#pragma unroll
            for (int m = 0; m < 4; ++m)
                af[m] = *reinterpret_cast<const s16x8*>(
                    &As[(wr * 64 + m * 16 + l15) * 64 + ((csl ^ rsw) << 3)]);
#pragma unroll
            for (int n = 0; n < 4; ++n)
                bfr[n] = *reinterpret_cast<const s16x8*>(
                    &Bs[(wc * 64 + n * 16 + l15) * 64 + ((csl ^ rsw) << 3)]);
            __builtin_amdgcn_s_setprio(1);
#pragma unroll
            for (int m = 0; m < 4; ++m)
#pragma unroll
                for (int n = 0; n < 4; ++n)
                    acc[m][n] = __builtin_amdgcn_mfma_f32_16x16x32_bf16(af[m], bfr[n], acc[m][n], 0, 0, 0);
            __builtin_amdgcn_s_setprio(0);
        }
    }

    const int rb = m0 + wr * 64, cb = n0 + wc * 64;
    if (z == 2) {
#pragma unroll
        for (int m = 0; m < 4; ++m) {
            int row = rb + m * 16 + l4 * 4;
            int b = row >> 11, s = row & 2047;
#pragma unroll
            for (int n = 0; n < 4; ++n) {
                int col = cb + n * 16 + l15;
                int h = col >> 6, dk = col & 63;
                u16x4 o;
                o.x = f2bf(acc[m][n][0]); o.y = f2bf(acc[m][n][1]);
                o.z = f2bf(acc[m][n][2]); o.w = f2bf(acc[m][n][3]);
                *reinterpret_cast<u16x4*>(&Vtb[(((b * N_HEAD + h) * D_HEAD + dk) << 11) + s]) = o;
            }
        }
    } else {
        unsigned short* C = (z == 0) ? Qb : Kb;
        const float alpha = (z == 0) ? 0.18033688011112042f : 1.0f;  // (1/8)*log2(e)
#pragma unroll
        for (int m = 0; m < 4; ++m)
#pragma unroll
            for (int n = 0; n < 4; ++n)
#pragma unroll
                for (int r = 0; r < 4; ++r)
                    C[(rb + m * 16 + l4 * 4 + r) * D_MODEL + cb + n * 16 + l15] =
                        f2bf(acc[m][n][r] * alpha);
    }
}

// ---------------- gemm_out: 128x64 tiles, BK=64, swizzled LDS ----------------

__global__ __launch_bounds__(256, 3) void gemm_out_kernel(
    const unsigned short* __restrict__ attnb, const unsigned short* __restrict__ wot,
    float* __restrict__ out)
{
    __shared__ unsigned short As[128 * 64];
    __shared__ unsigned short Bs[64 * 64];
    const int t = threadIdx.x, lane = t & 63, wid = t >> 6;
    const int wr = wid >> 1, wc = wid & 1;
    const int l15 = lane & 15, l4 = lane >> 4;

    const int orig = blockIdx.x;
    const int wg = (orig & 7) * 64 + (orig >> 3);
    const int m0 = (wg >> 4) * 128, n0 = (wg & 15) * 64;

    const int srow = t >> 3;
    const int srcoff = (((t & 7) ^ (srow & 7)) << 3);
    const unsigned short* Ab = attnb + (size_t)(m0 + srow) * D_MODEL + srcoff;
    const unsigned short* Bb = wot + (size_t)(n0 + srow) * D_MODEL + srcoff;
    const int ldsoff = t * 8;
    const int rsw = l15 & 7;

    f32x4 acc[4][2];
#pragma unroll
    for (int m = 0; m < 4; ++m)
#pragma unroll
        for (int n = 0; n < 2; ++n) acc[m][n] = (f32x4){0.f, 0.f, 0.f, 0.f};

    for (int k0 = 0; k0 < D_MODEL; k0 += 64) {
        __syncthreads();
#pragma unroll
        for (int i = 0; i < 4; ++i)
            GLOAD_LDS16(Ab + (size_t)(i * 32) * D_MODEL + k0, &As[i * 2048 + ldsoff]);
#pragma unroll
        for (int i = 0; i < 2; ++i)
            GLOAD_LDS16(Bb + (size_t)(i * 32) * D_MODEL + k0, &Bs[i * 2048 + ldsoff]);
        __syncthreads();

#pragma unroll
        for (int ks = 0; ks < 2; ++ks) {
            const int csl = ks * 4 + l4;
            s16x8 af[4], bfr[2];
#pragma unroll
            for (int m = 0; m < 4; ++m)
                af[m] = *reinterpret_cast<const s16x8*>(
                    &As[(wr * 64 + m * 16 + l15) * 64 + ((csl ^ rsw) << 3)]);
#pragma unroll
            for (int n = 0; n < 2; ++n)
                bfr[n] = *reinterpret_cast<const s16x8*>(
                    &Bs[(wc * 32 + n * 16 + l15) * 64 + ((csl ^ rsw) << 3)]);
            __builtin_amdgcn_s_setprio(1);
#pragma unroll
            for (int m = 0; m < 4; ++m)
#pragma unroll
                for (int n = 0; n < 2; ++n)
                    acc[m][n] = __builtin_amdgcn_mfma_f32_16x16x32_bf16(af[m], bfr[n], acc[m][n], 0, 0, 0);
            __builtin_amdgcn_s_setprio(0);
        }
    }

    const int rb = m0 + wr * 64, cb = n0 + wc * 32;
#pragma unroll
    for (int m = 0; m < 4; ++m)
#pragma unroll
        for (int n = 0; n < 2; ++n)
#pragma unroll
            for (int r = 0; r < 4; ++r)
                out[(rb + m * 16 + l4 * 4 + r) * D_MODEL + cb + n * 16 + l15] = acc[m][n][r];
}

// ---------------- flash attention v8: LDS-staged, uniform 12-tile chunks, LPT dispatch ----
// Fixed-base softmax exp2(s-8) (additive KV chunks). Best-measured configuration (r13).

__global__ __launch_bounds__(256, 4) void attn_kernel(
    const unsigned short* __restrict__ Qb, const unsigned short* __restrict__ Kb,
    const unsigned short* __restrict__ Vtb, unsigned short* __restrict__ Ob,
    unsigned short* __restrict__ Opart, float* __restrict__ larr)
{
    __shared__ unsigned short SMEM[8192];       // K dbuf [2][4096]
    __shared__ unsigned short SMEMV[8192];      // V dbuf [2][4096]

    const int t = threadIdx.x;
    const int lane = t & 63, wid = t >> 6;      // 4 waves
    const int l31 = lane & 31, l5 = lane >> 5;

    const int bid = blockIdx.x;                 // 0..959
    const int type = bid >> 5, bh = bid & 31;
    const int s = T_S[type], c = T_C[type];
    const int ta = c * 12;
    const int tbf = 2 * (s + 1);
    const int tb = (ta + 12 < tbf) ? ta + 12 : tbf;
    const bool split = (s >= 6);
    const int slot = bh * 24 + ((s < 12) ? (s - 6) * 2 + c : 12 + (s - 12) * 3 + c);

    const int b = bh >> 4, h = bh & 15;
    const int q0 = s << 7;
    const int qw = q0 + wid * 32;
    const int qrow = qw + l31;

    s16x8 qf[4];
#pragma unroll
    for (int ks = 0; ks < 4; ++ks)
        qf[ks] = *reinterpret_cast<const s16x8*>(
            &Qb[(size_t)(b * SEQ + qrow) * D_MODEL + h * D_HEAD + ks * 16 + l5 * 8]);

    f32x16 oacc[2];
#pragma unroll
    for (int d = 0; d < 2; ++d)
#pragma unroll
        for (int r = 0; r < 16; ++r) oacc[d][r] = 0.f;
    float lrun = 0.f;

    const int stK = (wid & 1) * 32;
    const int srow = lane >> 3;
    const int scol = ((lane & 7) ^ srow) * 8;
    const unsigned short* kgb = Kb + (size_t)(b * SEQ + stK + srow) * D_MODEL + h * D_HEAD + scol;
    const unsigned short* vgb = Vtb + ((size_t)(bh * D_HEAD + stK + srow) << 11) + scol;
    const int swz = (l31 & 7);

#define STAGE(bufidx, kvbase) do { \
    if (wid < 2) { \
        const unsigned short* kg = kgb + (size_t)(kvbase) * D_MODEL; \
        _Pragma("unroll") \
        for (int i_ = 0; i_ < 4; ++i_) \
            GLOAD_LDS16(kg + (size_t)(i_ * 8) * D_MODEL, &SMEM[(bufidx) * 4096 + (stK + i_ * 8) * 64]); \
    } else { \
        const unsigned short* vg = vgb + (kvbase); \
        _Pragma("unroll") \
        for (int i_ = 0; i_ < 4; ++i_) \
            GLOAD_LDS16(vg + ((size_t)(i_ * 8) << 11), &SMEMV[(bufidx) * 4096 + (stK + i_ * 8) * 64]); \
    } } while (0)

    STAGE(0, ta * 64);

    for (int ti = ta; ti < tb; ++ti) {
        const int cur = (ti - ta) & 1;
        const int kv0 = ti * 64;
        __builtin_amdgcn_sched_barrier(0);
        asm volatile("s_waitcnt vmcnt(0)" ::: "memory");
        __builtin_amdgcn_s_barrier();
        if (ti + 1 < tb) STAGE(cur ^ 1, (ti + 1) * 64);
        __builtin_amdgcn_sched_barrier(0);

        if (kv0 > qw + 31) continue;

        const unsigned short* KsC = &SMEM[cur * 4096];
        const unsigned short* VsC = &SMEMV[cur * 4096];

        f32x16 sacc[2];
#pragma unroll
        for (int kvsub = 0; kvsub < 2; ++kvsub) {
            const bool active = (kv0 + kvsub * 32 <= qw + 31);
            if (active) {
#pragma unroll
                for (int r = 0; r < 16; ++r) sacc[kvsub][r] = -8.0f;
                __builtin_amdgcn_s_setprio(1);
#pragma unroll
                for (int ks = 0; ks < 4; ++ks) {
                    s16x8 kf = *reinterpret_cast<const s16x8*>(
                        &KsC[(kvsub * 32 + l31) * 64 + (((2 * ks + l5) ^ swz) * 8)]);
                    sacc[kvsub] = __builtin_amdgcn_mfma_f32_32x32x16_bf16(kf, qf[ks], sacc[kvsub], 0, 0, 0);
                }
                __builtin_amdgcn_s_setprio(0);
                if (kv0 + kvsub * 32 + 31 > qw) {
                    int kvbase = kv0 + kvsub * 32 + 4 * l5;
#pragma unroll
                    for (int r = 0; r < 16; ++r) {
                        int kvg = kvbase + (r & 3) + 8 * (r >> 2);
                        sacc[kvsub][r] = (kvg > qrow) ? -1e30f : sacc[kvsub][r];
                    }
                }
#pragma unroll
                for (int r = 0; r < 16; ++r) sacc[kvsub][r] = EXP2(sacc[kvsub][r]);
            } else {
#pragma unroll
                for (int r = 0; r < 16; ++r) sacc[kvsub][r] = 0.f;
            }
        }

        float sred[16];
#pragma unroll
        for (int r = 0; r < 16; ++r) sred[r] = sacc[0][r] + sacc[1][r];
#pragma unroll
        for (int sj = 8; sj >= 1; sj >>= 1)
#pragma unroll
            for (int r = 0; r < 8; ++r)
                if (r < sj) sred[r] += sred[r + sj];
        lrun += sred[0] + __shfl_xor(sred[0], 32);

#pragma unroll
        for (int ks = 0; ks < 4; ++ks) {
            if (kv0 + (ks >> 1) * 32 > qw + 31) continue;
            const int kvsub = ks >> 1, bo = (ks & 1) * 8;
            unsigned a0 = cvtpk_bf16(sacc[kvsub][bo + 0], sacc[kvsub][bo + 1]);
            unsigned a1 = cvtpk_bf16(sacc[kvsub][bo + 2], sacc[kvsub][bo + 3]);
            unsigned a2 = cvtpk_bf16(sacc[kvsub][bo + 4], sacc[kvsub][bo + 5]);
            unsigned a3 = cvtpk_bf16(sacc[kvsub][bo + 6], sacc[kvsub][bo + 7]);
            asm volatile("v_permlane32_swap_b32 %0, %1" : "+v"(a0), "+v"(a2));
            asm volatile("v_permlane32_swap_b32 %0, %1" : "+v"(a1), "+v"(a3));
            u32x4 pw; pw.x = a0; pw.y = a1; pw.z = a2; pw.w = a3;
            s16x8 pf = __builtin_bit_cast(s16x8, pw);
            __builtin_amdgcn_s_setprio(1);
#pragma unroll
            for (int dsub = 0; dsub < 2; ++dsub) {
                s16x8 vf = *reinterpret_cast<const s16x8*>(
                    &VsC[(dsub * 32 + l31) * 64 + (((2 * ks + l5) ^ swz) * 8)]);
                oacc[dsub] = __builtin_amdgcn_mfma_f32_32x32x16_bf16(vf, pf, oacc[dsub], 0, 0, 0);
            }
            __builtin_amdgcn_s_setprio(0);
        }
    }
    __syncthreads();

    float inv = split ? 1.0f : (1.0f / lrun);
    const int orow = wid * 32 + l31;
#pragma unroll
    for (int dsub = 0; dsub < 2; ++dsub)
#pragma unroll
        for (int a = 0; a < 4; ++a) {
            unsigned w0 = cvtpk_bf16(oacc[dsub][4 * a + 0] * inv, oacc[dsub][4 * a + 1] * inv);
            unsigned w1 = cvtpk_bf16(oacc[dsub][4 * a + 2] * inv, oacc[dsub][4 * a + 3] * inv);
            int slt = (4 * dsub + a) ^ (orow & 7);
            uint2 pr; pr.x = w0; pr.y = w1;
            *reinterpret_cast<uint2*>(&SMEM[orow * 64 + slt * 8 + l5 * 4]) = pr;
        }
    __syncthreads();
    if (split) {
        unsigned short* Op = Opart + (size_t)slot * 8192;
#pragma unroll
        for (int i = 0; i < 4; ++i) {
            int g = i * 256 + t;
            int row = g >> 3, c16 = g & 7;
            int cs = (c16 ^ (row & 7)) * 8;
            *reinterpret_cast<s16x8*>(&Op[row * 64 + c16 * 8]) =
                *reinterpret_cast<const s16x8*>(&SMEM[row * 64 + cs]);
        }
        if (l5 == 0) larr[slot * 128 + orow] = lrun;
    } else {
#pragma unroll
        for (int i = 0; i < 4; ++i) {
            int g = i * 256 + t;
            int row = g >> 3, c16 = g & 7;
            int cs = (c16 ^ (row & 7)) * 8;
            s16x8 v = *reinterpret_cast<const s16x8*>(&SMEM[row * 64 + cs]);
            *reinterpret_cast<s16x8*>(
                &Ob[(size_t)(b * SEQ + q0 + row) * D_MODEL + h * D_HEAD + c16 * 8]) = v;
        }
    }
#undef STAGE
}

// ---------------- combine: Ob = (sum partials) / (sum l) for strips s>=6 ----------------

__global__ __launch_bounds__(256) void combine_kernel(
    const unsigned short* __restrict__ Opart, const float* __restrict__ larr,
    unsigned short* __restrict__ Ob)
{
    const int u = blockIdx.x;                   // 0..319 = bh*10 + (s-6)
    const int bh = u / 10, s = (u % 10) + 6;
    const int b = bh >> 4, h = bh & 15;
    const int base = bh * 24;
    const int s0 = (s < 12) ? base + (s - 6) * 2 : base + 12 + (s - 12) * 3;
    const int n = (s < 12) ? 2 : 3;
    const int t = threadIdx.x;
#pragma unroll
    for (int i = 0; i < 4; ++i) {
        int g = i * 256 + t;
        int row = g >> 3, c8 = (g & 7) * 8;
        float lsum = larr[s0 * 128 + row] + larr[(s0 + 1) * 128 + row];
        if (n == 3) lsum += larr[(s0 + 2) * 128 + row];
        float inv = 1.0f / lsum;
        float acc[8];
        {
            s16x8 va = *reinterpret_cast<const s16x8*>(&Opart[(size_t)s0 * 8192 + row * 64 + c8]);
            s16x8 vb = *reinterpret_cast<const s16x8*>(&Opart[(size_t)(s0 + 1) * 8192 + row * 64 + c8]);
#pragma unroll
            for (int j = 0; j < 8; ++j)
                acc[j] = bf2f((unsigned short)va[j]) + bf2f((unsigned short)vb[j]);
            if (n == 3) {
                s16x8 vc = *reinterpret_cast<const s16x8*>(&Opart[(size_t)(s0 + 2) * 8192 + row * 64 + c8]);
#pragma unroll
                for (int j = 0; j < 8; ++j) acc[j] += bf2f((unsigned short)vc[j]);
            }
        }
        union { s16x8 v; unsigned short e[8]; } o;
#pragma unroll
        for (int j = 0; j < 8; ++j) o.e[j] = f2bf(acc[j] * inv);
        *reinterpret_cast<s16x8*>(
            &Ob[(size_t)(b * SEQ + s * 128 + row) * D_MODEL + h * D_HEAD + c8]) = o.v;
    }
}

// ---------------- launch ----------------

extern "C" void kernel_launch(void* const* d_in, const int* in_sizes, int n_in,
                              void* d_out, int out_size, void* d_ws, size_t ws_size,
                              hipStream_t stream) {
    (void)in_sizes; (void)n_in; (void)out_size; (void)ws_size;
    const float* x  = (const float*)d_in[0];
    const float* wq = (const float*)d_in[1];
    const float* wk = (const float*)d_in[2];
    const float* wv = (const float*)d_in[3];
    const float* wo = (const float*)d_in[4];
    float* out = (float*)d_out;

    char* ws = (char*)d_ws;
    unsigned short* xb  = (unsigned short*)(ws);
    unsigned short* wqt = (unsigned short*)(ws + (8u  << 20));
    unsigned short* wkt = (unsigned short*)(ws + (10u << 20));
    unsigned short* wvt = (unsigned short*)(ws + (12u << 20));
    unsigned short* wot = (unsigned short*)(ws + (14u << 20));
    unsigned short* Qb  = (unsigned short*)(ws + (16u << 20));
    unsigned short* Kb  = (unsigned short*)(ws + (24u << 20));
    unsigned short* Vtb = (unsigned short*)(ws + (32u << 20));
    unsigned short* Ob  = (unsigned short*)(ws + (40u << 20));
    unsigned short* Opart = xb;                       // 768 slots x 128x64 bf16 = 12 MB
    float*          larr  = (float*)wvt;              // 768 x 128 fp32 (dead after qkv)

    hipLaunchKernelGGL(cvt_all_kernel, dim3(5120), dim3(256), 0, stream,
                       x, xb, wq, wk, wv, wo, wqt, wkt, wvt, wot);

    hipLaunchKernelGGL(gemm_qkv_kernel, dim3(768), dim3(256), 0, stream,
                       xb, wqt, wkt, wvt, Qb, Kb, Vtb);
    hipLaunchKernelGGL(attn_kernel, dim3(960), dim3(256), 0, stream,
                       Qb, Kb, Vtb, Ob, Opart, larr);
    hipLaunchKernelGGL(combine_kernel, dim3(320), dim3(256), 0, stream, Opart, larr, Ob);
    hipLaunchKernelGGL(gemm_out_kernel, dim3(512), dim3(256), 0, stream, Ob, wot, out);
}